// Round 7
// baseline (352.578 us; speedup 1.0000x reference)
//
#include <hip/hip_runtime.h>
#include <hip/hip_fp16.h>
#include <cstdint>

#define BATCH 512
#define CIN   64
#define HH    32
#define WW    64
#define HW    2048
#define C1    32
#define C2    16
#define C3    8
#define C4    4
#define NOUT  256
#define KFC   8192
#define NODES 128
#define KS    16                      // FC K-split
#define GF_SIZE (BATCH * NODES * CIN)

typedef __attribute__((ext_vector_type(8))) short bfrag;   // 8 bf16 (4 VGPRs)
typedef __attribute__((ext_vector_type(4))) float ffrag;   // 4 fp32 acc

__device__ __forceinline__ ushort bf_trunc(float f) { return (ushort)(__float_as_uint(f) >> 16); }
__device__ __forceinline__ float  bf_truncf(float f) { return __uint_as_float(__float_as_uint(f) & 0xffff0000u); }
__device__ __forceinline__ ushort f2bf(float f) {
  uint32_t u = __float_as_uint(f);
  return (ushort)((u + 0x7fffu + ((u >> 16) & 1u)) >> 16);
}
__device__ __forceinline__ uint32_t pack2(float a, float b) {
  return (uint32_t)f2bf(a) | ((uint32_t)f2bf(b) << 16);
}
__device__ __forceinline__ uint32_t packhi2(float a, float b) {
  return (uint32_t)bf_trunc(a) | ((uint32_t)bf_trunc(b) << 16);
}
__device__ __forceinline__ ushort f2h(float f) { return __half_as_ushort(__float2half_rn(f)); }
__device__ __forceinline__ uint32_t packh2(float a, float b) {
  return (uint32_t)f2h(a) | ((uint32_t)f2h(b) << 16);
}
__device__ __forceinline__ float h2f(uint32_t u) { return __half2float(__ushort_as_half((ushort)u)); }

// ---------------------------------------------------------------------------
// K1: conv1 (1x1, 64->32) + conv2 (3x3 pad1, 32->16) fused, MFMA bf16.
// Round-6: latency-bound fix. 4-row tiles -> h1s [6][66][64B] = 25344 B ->
// 5-6 blocks/CU (was 3). Phase A: explicit 2-deep prefetch pipeline (16-float
// double buffer, fully unrolled = static reg indexing). Phase B: w2 taps in
// two passes (5+4) to halve live w2 VGPRs; acc[4] carried across passes.
// h2 stored as fp16 NHWC (halves write traffic; ~2^-11 rel err, negligible).
// x NCHW fp32 -> h2 fp16 [cb][32][64][16ch].  grid (8, cb), 256 thr.
// ---------------------------------------------------------------------------
__global__ __launch_bounds__(256, 5) void k_conv12(
    const float* __restrict__ x, const float* __restrict__ w11, const float* __restrict__ b11,
    const float* __restrict__ w12, const float* __restrict__ b12,
    ushort* __restrict__ h2, int b0)
{
  __shared__ __align__(16) char h1s[6 * 66 * 64];   // 25344 B
  const int tid = threadIdx.x;
  const int l   = tid & 63;
  const int wv  = tid >> 6;    // 0..3
  const int lr  = l & 15;
  const int lg  = l >> 4;
  const int r0  = blockIdx.x * 4;
  const int bg  = b0 + blockIdx.y;
  const float* xb = x + (size_t)bg * CIN * HW;

  // zero the padded columns (colb = 0 and 65) of all 6 rows
  if (tid < 96) {
    int cell = tid >> 3, q = tid & 7;
    int row = cell >> 1, colb = (cell & 1) ? 65 : 0;
    *(uint2*)(h1s + ((row * 66 + colb) << 6) + q * 8) = uint2{0u, 0u};
  }

  // W1 fragments from global (hi/lo split keeps W fp32-grade)
  bfrag w1h[2][2], w1l[2][2];   // [Mtile][kstep]
  #pragma unroll
  for (int m = 0; m < 2; ++m) {
    #pragma unroll
    for (int ks = 0; ks < 2; ++ks) {
      const float* wp = w11 + (m * 16 + lr) * 64 + ks * 32 + lg * 8;
      #pragma unroll
      for (int e = 0; e < 8; ++e) {
        float v = wp[e];
        w1h[m][ks][e] = (short)bf_trunc(v);
        w1l[m][ks][e] = (short)f2bf(v - bf_truncf(v));
      }
    }
  }
  float bias1[2][4];
  #pragma unroll
  for (int m = 0; m < 2; ++m) {
    #pragma unroll
    for (int r = 0; r < 4; ++r) bias1[m][r] = b11[m * 16 + lg * 4 + r];
  }

  // ---- Phase A: conv1 -> h1 LDS. 24 tiles (6 rows x 4 col-tiles), 6/wave,
  // explicit double-buffered prefetch.
  float bufA[16], bufB[16];

  auto loadx16 = [&](int nt, float (&buf)[16]) {
    const int ry = nt >> 2, col0 = (nt & 3) << 4;
    const int y  = r0 - 1 + ry;
    if (y >= 0 && y < HH) {
      const float* xp = xb + y * WW + col0 + lr;
      #pragma unroll
      for (int ks = 0; ks < 2; ++ks)
        #pragma unroll
        for (int e = 0; e < 8; ++e)
          buf[ks * 8 + e] = xp[(ks * 32 + lg * 8 + e) * HW];
    } else {
      #pragma unroll
      for (int j = 0; j < 16; ++j) buf[j] = 0.f;
    }
  };

  auto comp_tile = [&](int nt, const float (&buf)[16]) {
    const int ry = nt >> 2, col0 = (nt & 3) << 4;
    const int y  = r0 - 1 + ry;
    const bool valid = (y >= 0) && (y < HH);
    const int colb = col0 + 1 + lr;
    bfrag xh[2];
    #pragma unroll
    for (int ks = 0; ks < 2; ++ks)
      #pragma unroll
      for (int e = 0; e < 8; ++e)
        xh[ks][e] = (short)f2bf(buf[ks * 8 + e]);
    ffrag a0 = {0.f, 0.f, 0.f, 0.f}, a1 = {0.f, 0.f, 0.f, 0.f};
    #pragma unroll
    for (int ks = 0; ks < 2; ++ks) {
      a0 = __builtin_amdgcn_mfma_f32_16x16x32_bf16(w1h[0][ks], xh[ks], a0, 0, 0, 0);
      a0 = __builtin_amdgcn_mfma_f32_16x16x32_bf16(w1l[0][ks], xh[ks], a0, 0, 0, 0);
      a1 = __builtin_amdgcn_mfma_f32_16x16x32_bf16(w1h[1][ks], xh[ks], a1, 0, 0, 0);
      a1 = __builtin_amdgcn_mfma_f32_16x16x32_bf16(w1l[1][ks], xh[ks], a1, 0, 0, 0);
    }
    #pragma unroll
    for (int m = 0; m < 2; ++m) {
      uint2 sv;
      if (valid) {
        float v0 = fmaxf((m ? a1[0] : a0[0]) + bias1[m][0], 0.f);
        float v1 = fmaxf((m ? a1[1] : a0[1]) + bias1[m][1], 0.f);
        float v2 = fmaxf((m ? a1[2] : a0[2]) + bias1[m][2], 0.f);
        float v3 = fmaxf((m ? a1[3] : a0[3]) + bias1[m][3], 0.f);
        sv = uint2{pack2(v0, v1), pack2(v2, v3)};
      } else {
        sv = uint2{0u, 0u};
      }
      int chunk = (m * 2 + (lg >> 1)) ^ ((colb >> 1) & 3);
      char* dst = h1s + ((ry * 66 + colb) << 6) + (chunk << 4) + (lg & 1) * 8;
      *(uint2*)dst = sv;
    }
  };

  loadx16(wv * 6 + 0, bufA);
  #pragma unroll
  for (int i = 0; i < 6; ++i) {
    if (i < 5) loadx16(wv * 6 + i + 1, (i & 1) ? bufA : bufB);
    if (i & 1) comp_tile(wv * 6 + i, bufB);
    else       comp_tile(wv * 6 + i, bufA);
  }
  __syncthreads();

  // ---- Phase B: conv2 (9 taps, K=32), 16 tiles, 4/wave, taps in 2 passes.
  ffrag acc2[4] = {{0.f,0.f,0.f,0.f},{0.f,0.f,0.f,0.f},{0.f,0.f,0.f,0.f},{0.f,0.f,0.f,0.f}};
  #pragma unroll
  for (int pass = 0; pass < 2; ++pass) {
    const int t0 = pass ? 5 : 0;
    const int tn = pass ? 4 : 5;
    bfrag wh[5], wl[5];
    #pragma unroll
    for (int tt = 0; tt < 5; ++tt) {
      if (tt < tn) {
        const float* wp = w12 + lr * 288 + (t0 + tt);
        #pragma unroll
        for (int e = 0; e < 8; ++e) {
          float v = wp[(lg * 8 + e) * 9];
          wh[tt][e] = (short)bf_trunc(v);
          wl[tt][e] = (short)f2bf(v - bf_truncf(v));
        }
      }
    }
    #pragma unroll
    for (int i = 0; i < 4; ++i) {
      const int nt   = wv * 4 + i;
      const int ryo  = nt >> 2;
      const int col0 = (nt & 3) << 4;
      #pragma unroll
      for (int tt = 0; tt < 5; ++tt) {
        if (tt < tn) {
          const int t = t0 + tt, ky = t / 3, kx = t - ky * 3;
          const int colb  = col0 + lr + kx;
          const int chunk = lg ^ ((colb >> 1) & 3);
          const bfrag hv = *(const bfrag*)(h1s + (((ryo + ky) * 66 + colb) << 6) + (chunk << 4));
          acc2[i] = __builtin_amdgcn_mfma_f32_16x16x32_bf16(wh[tt], hv, acc2[i], 0, 0, 0);
          acc2[i] = __builtin_amdgcn_mfma_f32_16x16x32_bf16(wl[tt], hv, acc2[i], 0, 0, 0);
        }
      }
    }
  }
  float bias2[4];
  #pragma unroll
  for (int r = 0; r < 4; ++r) bias2[r] = b12[lg * 4 + r];
  #pragma unroll
  for (int i = 0; i < 4; ++i) {
    const int nt   = wv * 4 + i;
    const int px   = (r0 + (nt >> 2)) * WW + ((nt & 3) << 4) + lr;
    uint2 o;
    o.x = packh2(fmaxf(acc2[i][0] + bias2[0], 0.f), fmaxf(acc2[i][1] + bias2[1], 0.f));
    o.y = packh2(fmaxf(acc2[i][2] + bias2[2], 0.f), fmaxf(acc2[i][3] + bias2[3], 0.f));
    *(uint2*)(h2 + ((size_t)blockIdx.y * HW + px) * 16 + lg * 4) = o;
  }
}

// ---------------------------------------------------------------------------
// K2: conv3 (1x1, 16->8, relu) + conv4 (3x3 pad1, 8->4, relu), fused (VALU).
// h2 fp16 NHWC -> h4 bf16 hi/lo planes [cb][8192] (FC flatten order).
// ---------------------------------------------------------------------------
__global__ __launch_bounds__(256) void k_conv34(
    const ushort* __restrict__ h2, const float* __restrict__ w21, const float* __restrict__ b21,
    const float* __restrict__ w22, const float* __restrict__ b22,
    ushort* __restrict__ h4h, ushort* __restrict__ h4l)
{
  __shared__ float h3s[18][64][9];
  __shared__ float __align__(16) w21s[128];
  __shared__ float __align__(16) w22s[288];
  const int tid = threadIdx.x;
  const int r0  = blockIdx.x * 16;
  const size_t b = blockIdx.y;

  for (int i = tid; i < 128; i += 256) w21s[(i & 15) * 8 + (i >> 4)] = w21[i];
  for (int i = tid; i < 288; i += 256) {
    int o = i / 72, r = i - o * 72, c = r / 9, tap = r - c * 9;
    w22s[(tap * 8 + c) * 4 + o] = w22[i];
  }
  __syncthreads();

  for (int p = tid; p < 18 * 64; p += 256) {
    const int ry = p >> 6, wc = p & 63;
    const int y  = r0 - 1 + ry;
    float* hd = &h3s[ry][wc][0];
    if (y >= 0 && y < HH) {
      const uint4* hp = (const uint4*)(h2 + ((b * HH + y) * WW + wc) * 16);
      uint4 ua = hp[0], ub = hp[1];
      uint32_t uw[8] = {ua.x, ua.y, ua.z, ua.w, ub.x, ub.y, ub.z, ub.w};
      float xv[16];
      #pragma unroll
      for (int j = 0; j < 8; ++j) {
        xv[2*j]   = h2f(uw[j] & 0xffffu);
        xv[2*j+1] = h2f(uw[j] >> 16);
      }
      float acc[C3];
      #pragma unroll
      for (int o = 0; o < C3; ++o) acc[o] = b21[o];
      #pragma unroll
      for (int c = 0; c < 16; ++c) {
        const float4* wr = (const float4*)&w21s[c * 8];
        float4 a = wr[0], d = wr[1];
        float v = xv[c];
        acc[0] = fmaf(v, a.x, acc[0]); acc[1] = fmaf(v, a.y, acc[1]);
        acc[2] = fmaf(v, a.z, acc[2]); acc[3] = fmaf(v, a.w, acc[3]);
        acc[4] = fmaf(v, d.x, acc[4]); acc[5] = fmaf(v, d.y, acc[5]);
        acc[6] = fmaf(v, d.z, acc[6]); acc[7] = fmaf(v, d.w, acc[7]);
      }
      #pragma unroll
      for (int c = 0; c < C3; ++c) hd[c] = fmaxf(acc[c], 0.f);
    } else {
      #pragma unroll
      for (int c = 0; c < C3; ++c) hd[c] = 0.f;
    }
  }
  __syncthreads();

  for (int p = tid; p < 1024; p += 256) {
    const int yl = p >> 6, wc = p & 63, ry = yl + 1;
    float acc[C4] = {b22[0], b22[1], b22[2], b22[3]};
    #pragma unroll
    for (int ky = 0; ky < 3; ++ky) {
      #pragma unroll
      for (int kx = 0; kx < 3; ++kx) {
        const int wcc = wc + kx - 1;
        if (wcc < 0 || wcc >= WW) continue;
        const float* hb = &h3s[ry + ky - 1][wcc][0];
        const int tap = ky * 3 + kx;
        #pragma unroll
        for (int c = 0; c < C3; ++c) {
          float v = hb[c];
          float4 w4 = *(const float4*)&w22s[(tap * 8 + c) * 4];
          acc[0] = fmaf(v, w4.x, acc[0]); acc[1] = fmaf(v, w4.y, acc[1]);
          acc[2] = fmaf(v, w4.z, acc[2]); acc[3] = fmaf(v, w4.w, acc[3]);
        }
      }
    }
    const size_t base = b * KFC + (r0 + yl) * WW + wc;
    #pragma unroll
    for (int o = 0; o < C4; ++o) {
      float v = fmaxf(acc[o], 0.f);
      h4h[base + (size_t)o * HW] = bf_trunc(v);
      h4l[base + (size_t)o * HW] = f2bf(v - bf_truncf(v));
    }
  }
}

// ---------------------------------------------------------------------------
// K2b: fcw fp32 -> bf16 hi/lo planes (once per launch, deterministic)
// ---------------------------------------------------------------------------
__global__ __launch_bounds__(256) void k_cvt_fcw(
    const float* __restrict__ w, ushort* __restrict__ hi, ushort* __restrict__ lo)
{
  const int i = (blockIdx.x * 256 + threadIdx.x) * 8;
  const float4 a = *(const float4*)(w + i);
  const float4 b = *(const float4*)(w + i + 4);
  uint4 hv, lv;
  hv.x = packhi2(a.x, a.y); hv.y = packhi2(a.z, a.w);
  hv.z = packhi2(b.x, b.y); hv.w = packhi2(b.z, b.w);
  lv.x = pack2(a.x - bf_truncf(a.x), a.y - bf_truncf(a.y));
  lv.y = pack2(a.z - bf_truncf(a.z), a.w - bf_truncf(a.w));
  lv.z = pack2(b.x - bf_truncf(b.x), b.y - bf_truncf(b.y));
  lv.w = pack2(b.z - bf_truncf(b.z), b.w - bf_truncf(b.w));
  *(uint4*)(hi + i) = hv;
  *(uint4*)(lo + i) = lv;
}

// ---------------------------------------------------------------------------
// K3: FC GEMM, MFMA bf16 3-product (hi/lo), K split KS-way, deterministic.
// ---------------------------------------------------------------------------
__global__ __launch_bounds__(256) void k_fc(
    const ushort* __restrict__ Ahp, const ushort* __restrict__ Alp,
    const ushort* __restrict__ Bhp, const ushort* __restrict__ Blp,
    float* __restrict__ zpart, int cb)
{
  const int tid = threadIdx.x;
  const int l   = tid & 63;
  const int wv  = tid >> 6;
  const int lr  = l & 15;
  const int lg  = l >> 4;
  const int m0  = blockIdx.x * 64 + (wv >> 1) * 32;
  const int n0  = blockIdx.y * 64 + (wv & 1) * 32;
  const int k0  = blockIdx.z * (KFC / KS);     // 512 per split

  int mrow[2], nrow[2];
  #pragma unroll
  for (int t = 0; t < 2; ++t) {
    int m = m0 + t * 16 + lr;
    mrow[t] = m < cb ? m : cb - 1;             // clamp; masked at write
    nrow[t] = n0 + t * 16 + lr;
  }
  ffrag acc[2][2] = {};

  #pragma unroll 1
  for (int kc = 0; kc < (KFC / KS) / 32; ++kc) {
    const int k = k0 + kc * 32 + lg * 8;
    bfrag ah[2], al[2], bh[2], bl[2];
    #pragma unroll
    for (int t = 0; t < 2; ++t) {
      ah[t] = *(const bfrag*)(Ahp + (size_t)mrow[t] * KFC + k);
      al[t] = *(const bfrag*)(Alp + (size_t)mrow[t] * KFC + k);
      bh[t] = *(const bfrag*)(Bhp + (size_t)nrow[t] * KFC + k);
      bl[t] = *(const bfrag*)(Blp + (size_t)nrow[t] * KFC + k);
    }
    #pragma unroll
    for (int mt = 0; mt < 2; ++mt) {
      #pragma unroll
      for (int nt = 0; nt < 2; ++nt) {
        acc[mt][nt] = __builtin_amdgcn_mfma_f32_16x16x32_bf16(ah[mt], bh[nt], acc[mt][nt], 0, 0, 0);
        acc[mt][nt] = __builtin_amdgcn_mfma_f32_16x16x32_bf16(ah[mt], bl[nt], acc[mt][nt], 0, 0, 0);
        acc[mt][nt] = __builtin_amdgcn_mfma_f32_16x16x32_bf16(al[mt], bh[nt], acc[mt][nt], 0, 0, 0);
      }
    }
  }

  #pragma unroll
  for (int mt = 0; mt < 2; ++mt) {
    #pragma unroll
    for (int r = 0; r < 4; ++r) {
      const int m = m0 + mt * 16 + lg * 4 + r;
      if (m < cb) {
        #pragma unroll
        for (int nt = 0; nt < 2; ++nt)
          zpart[((size_t)blockIdx.z * cb + m) * NOUT + n0 + nt * 16 + lr] = acc[mt][nt][r];
      }
    }
  }
}

// ---------------------------------------------------------------------------
// K5: fused coord + bilinear gather. One wave per (b,node).
// ---------------------------------------------------------------------------
__global__ __launch_bounds__(256) void k_gather(
    const float* __restrict__ x, const float* __restrict__ zpart,
    const float* __restrict__ fcb, float* __restrict__ out, int cb, int b0)
{
  const int bid = blockIdx.x;
  int bl, g;
  if ((cb & 7) == 0) {
    const int xcd = bid & 7;
    const int j   = bid >> 3;
    g  = j & 31;                 // 32 blocks per image
    bl = (j >> 5) * 8 + xcd;
  } else {
    bl = bid >> 5;
    g  = bid & 31;
  }
  const int node = g * 4 + (threadIdx.x >> 6);
  const int l    = threadIdx.x & 63;
  const int bg   = b0 + bl;

  float val = 0.f;
  if (l < 2 * KS) {
    const int kb = l >> 1, comp = l & 1;
    val = zpart[((size_t)kb * cb + bl) * NOUT + node * 2 + comp];
  }
  #pragma unroll
  for (int off = 2; off < 2 * KS; off <<= 1) val += __shfl_xor(val, off);
  const float z0 = __shfl(val, 0) + fcb[node * 2 + 0];
  const float z1 = __shfl(val, 1) + fcb[node * 2 + 1];
  const float ch = 31.f / (1.f + __expf(-3.f * z0));
  const float cw = 63.f / (1.f + __expf(-3.f * z1));

  if (l < 2)
    out[GF_SIZE + (((size_t)bg * NODES + node) << 1) + l] = l ? cw : ch;

  const float chv = fminf(fmaxf(ch, 0.f), 31.f);
  const float cwv = fminf(fmaxf(cw, 0.f), 63.f);
  const float fh = floorf(chv), fw = floorf(cwv);
  const int h0 = (int)fh, h1i = (int)ceilf(chv);
  const int w0 = (int)fw, w1i = (int)ceilf(cwv);
  const float oh = chv - fh, ow = cwv - fw;
  const float* xbp = x + ((size_t)bg * CIN + l) * HW;
  const float v_lt = xbp[h0 * WW + w0];
  const float v_rt = xbp[h1i * WW + w0];
  const float v_lb = xbp[h0 * WW + w1i];
  const float v_rb = xbp[h1i * WW + w1i];
  const float vt = v_lt + oh * (v_rt - v_lt);
  const float vb = v_lb + oh * (v_rb - v_lb);
  out[((size_t)bg * NODES + node) * CIN + l] = vt + ow * (vb - vt);
}

// ---------------------------------------------------------------------------
extern "C" void kernel_launch(void* const* d_in, const int* in_sizes, int n_in,
                              void* d_out, int out_size, void* d_ws, size_t ws_size,
                              hipStream_t stream)
{
  (void)in_sizes; (void)n_in; (void)out_size;
  const float* x   = (const float*)d_in[0];
  const float* w11 = (const float*)d_in[1];
  const float* b11 = (const float*)d_in[2];
  const float* w12 = (const float*)d_in[3];
  const float* b12 = (const float*)d_in[4];
  const float* w21 = (const float*)d_in[5];
  const float* b21 = (const float*)d_in[6];
  const float* w22 = (const float*)d_in[7];
  const float* b22 = (const float*)d_in[8];
  const float* fcw = (const float*)d_in[9];
  const float* fcb = (const float*)d_in[10];
  float* out = (float*)d_out;
  char* wsb  = (char*)d_ws;

  // per-b: h2 fp16 (65536) + h4 hi/lo bf16 (2x16384) + zpart (KS*256*4)
  const size_t perB  = 65536 + 16384 + 16384 + (size_t)KS * NOUT * 4;
  const size_t fixed = 2 * 4194304;            // fcw hi/lo planes
  size_t avail = ws_size > fixed ? ws_size - fixed : perB;
  size_t cbmax = avail / perB;
  int CB = (int)(cbmax < (size_t)BATCH ? cbmax : (size_t)BATCH);
  if (CB < 1) CB = 1;

  char* p = wsb;
  ushort* h2v  = (ushort*)p;  p += (size_t)CB * 65536;
  ushort* h4h  = (ushort*)p;  p += (size_t)CB * 16384;
  ushort* h4l  = (ushort*)p;  p += (size_t)CB * 16384;
  float*  zpv  = (float*)p;   p += (size_t)CB * KS * NOUT * 4;
  ushort* fcwh = (ushort*)p;  p += 4194304;
  ushort* fcwl = (ushort*)p;

  k_cvt_fcw<<<dim3(NOUT * KFC / (256 * 8)), 256, 0, stream>>>(fcw, fcwh, fcwl);

  for (int b0 = 0; b0 < BATCH; b0 += CB) {
    const int cb = (BATCH - b0 < CB) ? (BATCH - b0) : CB;
    k_conv12<<<dim3(8, cb), 256, 0, stream>>>(x, w11, b11, w12, b12, h2v, b0);
    k_conv34<<<dim3(2, cb), 256, 0, stream>>>(h2v, w21, b21, w22, b22, h4h, h4l);
    k_fc<<<dim3((cb + 63) / 64, 4, KS), 256, 0, stream>>>(h4h, h4l, fcwh, fcwl, zpv, cb);
    k_gather<<<dim3(cb * 32), 256, 0, stream>>>(x, zpv, fcb, out, cb, b0);
  }
}

// Round 8
// 278.236 us; speedup vs baseline: 1.2672x; 1.2672x over previous
//
#include <hip/hip_runtime.h>
#include <hip/hip_fp16.h>
#include <cstdint>

#define BATCH 512
#define CIN   64
#define HH    32
#define WW    64
#define HW    2048
#define C1    32
#define C2    16
#define C3    8
#define C4    4
#define NOUT  256
#define KFC   8192
#define NODES 128
#define KS    16                      // FC K-split
#define GF_SIZE (BATCH * NODES * CIN)

typedef __attribute__((ext_vector_type(8))) short bfrag;   // 8 bf16 (4 VGPRs)
typedef __attribute__((ext_vector_type(4))) float ffrag;   // 4 fp32 acc

__device__ __forceinline__ ushort bf_trunc(float f) { return (ushort)(__float_as_uint(f) >> 16); }
__device__ __forceinline__ float  bf_truncf(float f) { return __uint_as_float(__float_as_uint(f) & 0xffff0000u); }
__device__ __forceinline__ ushort f2bf(float f) {
  uint32_t u = __float_as_uint(f);
  return (ushort)((u + 0x7fffu + ((u >> 16) & 1u)) >> 16);
}
__device__ __forceinline__ uint32_t pack2(float a, float b) {
  return (uint32_t)f2bf(a) | ((uint32_t)f2bf(b) << 16);
}
__device__ __forceinline__ uint32_t packhi2(float a, float b) {
  return (uint32_t)bf_trunc(a) | ((uint32_t)bf_trunc(b) << 16);
}
__device__ __forceinline__ ushort f2h(float f) { return __half_as_ushort(__float2half_rn(f)); }
__device__ __forceinline__ uint32_t packh2(float a, float b) {
  return (uint32_t)f2h(a) | ((uint32_t)f2h(b) << 16);
}
__device__ __forceinline__ float h2f(uint32_t u) { return __half2float(__ushort_as_half((ushort)u)); }
__device__ __forceinline__ float bf2f(ushort u) { return __uint_as_float(((uint32_t)u) << 16); }

// ---------------------------------------------------------------------------
// K0: x NCHW fp32 -> xt NHWC bf16 (RTN). One block = (image b, 4 rows).
// Reads coalesced along w (lane = col); writes 128 B/lane contiguous.
// grid (8, BATCH), block 256 (wave = one row of 64 px).
// ---------------------------------------------------------------------------
__global__ __launch_bounds__(256) void k_xpose(
    const float* __restrict__ x, ushort* __restrict__ xt)
{
  const int b   = blockIdx.y;
  const int row = blockIdx.x * 4 + (threadIdx.x >> 6);
  const int px  = threadIdx.x & 63;
  const float* xp = x + (size_t)b * CIN * HW + row * WW + px;
  uint32_t packed[32];
  #pragma unroll
  for (int c = 0; c < 32; ++c) {
    float v0 = xp[(size_t)(2 * c) * HW];
    float v1 = xp[(size_t)(2 * c + 1) * HW];
    packed[c] = pack2(v0, v1);
  }
  ushort* op = xt + ((size_t)b * HW + row * WW + px) * CIN;
  #pragma unroll
  for (int q = 0; q < 8; ++q)
    *(uint4*)(op + q * 8) = *(const uint4*)&packed[q * 4];
}

// ---------------------------------------------------------------------------
// K1: conv1 (1x1, 64->32) + conv2 (3x3 pad1, 32->16) fused, MFMA bf16.
// Round-8: consumes xt (NHWC bf16) -> Phase A per tile = TWO coalesced 16 B
// loads (8 consecutive ch each), zero convert VALU, 2-deep frag prefetch.
// Weights stay hi/lo split (fp32-grade). h1 bf16 in LDS (swizzled, as R2-R5).
// NO launch_bounds min-occupancy arg (R3/R7 lesson: it forces spill).
// LDS = h1 [10][66][64B] = 42240 B -> 3 blocks/CU.
// xt NHWC bf16 -> h2 fp16 NHWC [cb][32][64][16].  grid (4, cb), 256 thr.
// ---------------------------------------------------------------------------
__global__ __launch_bounds__(256) void k_conv12(
    const ushort* __restrict__ xt, const float* __restrict__ w11, const float* __restrict__ b11,
    const float* __restrict__ w12, const float* __restrict__ b12,
    ushort* __restrict__ h2, int b0)
{
  __shared__ __align__(16) char h1s[10 * 66 * 64];   // 42240 B
  const int tid = threadIdx.x;
  const int l   = tid & 63;
  const int wv  = tid >> 6;    // 0..3
  const int lr  = l & 15;
  const int lg  = l >> 4;
  const int r0  = blockIdx.x * 8;
  const int bg  = b0 + blockIdx.y;
  const ushort* xtb = xt + (size_t)bg * HW * CIN;

  // zero the padded columns (colb = 0 and 65) of all 10 rows
  if (tid < 160) {
    int row = tid >> 4, half = (tid >> 3) & 1, q = tid & 7;
    int cell = row * 66 + (half ? 65 : 0);
    *(uint2*)(h1s + (cell << 6) + q * 8) = uint2{0u, 0u};
  }

  // W1 fragments from global (hi/lo split keeps W fp32-grade)
  bfrag w1h[2][2], w1l[2][2];   // [Mtile][kstep]
  #pragma unroll
  for (int m = 0; m < 2; ++m) {
    #pragma unroll
    for (int ks = 0; ks < 2; ++ks) {
      const float* wp = w11 + (m * 16 + lr) * 64 + ks * 32 + lg * 8;
      #pragma unroll
      for (int e = 0; e < 8; ++e) {
        float v = wp[e];
        w1h[m][ks][e] = (short)bf_trunc(v);
        w1l[m][ks][e] = (short)f2bf(v - bf_truncf(v));
      }
    }
  }
  float bias1[2][4];
  #pragma unroll
  for (int m = 0; m < 2; ++m) {
    #pragma unroll
    for (int r = 0; r < 4; ++r) bias1[m][r] = b11[m * 16 + lg * 4 + r];
  }

  // ---- Phase A: conv1 -> h1 LDS. 40 tiles (10 rows x 4 col-tiles), 10/wave,
  // 2-deep fragment prefetch; loads are coalesced dwordx4 from xt.
  auto ldfrag = [&](int nt, bfrag& f0, bfrag& f1) {
    const int ry = nt >> 2, col0 = (nt & 3) << 4;
    const int y  = r0 - 1 + ry;
    if (y >= 0 && y < HH) {
      const ushort* xp = xtb + (size_t)(y * WW + col0 + lr) * CIN + lg * 8;
      f0 = *(const bfrag*)xp;
      f1 = *(const bfrag*)(xp + 32);
    } else {
      #pragma unroll
      for (int e = 0; e < 8; ++e) { f0[e] = 0; f1[e] = 0; }
    }
  };
  auto comp = [&](int nt, bfrag f0, bfrag f1) {
    const int ry = nt >> 2, col0 = (nt & 3) << 4;
    const int y  = r0 - 1 + ry;
    const bool valid = (y >= 0) && (y < HH);
    const int colb = col0 + 1 + lr;
    ffrag a0 = {0.f, 0.f, 0.f, 0.f}, a1 = {0.f, 0.f, 0.f, 0.f};
    a0 = __builtin_amdgcn_mfma_f32_16x16x32_bf16(w1h[0][0], f0, a0, 0, 0, 0);
    a0 = __builtin_amdgcn_mfma_f32_16x16x32_bf16(w1l[0][0], f0, a0, 0, 0, 0);
    a0 = __builtin_amdgcn_mfma_f32_16x16x32_bf16(w1h[0][1], f1, a0, 0, 0, 0);
    a0 = __builtin_amdgcn_mfma_f32_16x16x32_bf16(w1l[0][1], f1, a0, 0, 0, 0);
    a1 = __builtin_amdgcn_mfma_f32_16x16x32_bf16(w1h[1][0], f0, a1, 0, 0, 0);
    a1 = __builtin_amdgcn_mfma_f32_16x16x32_bf16(w1l[1][0], f0, a1, 0, 0, 0);
    a1 = __builtin_amdgcn_mfma_f32_16x16x32_bf16(w1h[1][1], f1, a1, 0, 0, 0);
    a1 = __builtin_amdgcn_mfma_f32_16x16x32_bf16(w1l[1][1], f1, a1, 0, 0, 0);
    #pragma unroll
    for (int m = 0; m < 2; ++m) {
      uint2 sv;
      if (valid) {
        float v0 = fmaxf((m ? a1[0] : a0[0]) + bias1[m][0], 0.f);
        float v1 = fmaxf((m ? a1[1] : a0[1]) + bias1[m][1], 0.f);
        float v2 = fmaxf((m ? a1[2] : a0[2]) + bias1[m][2], 0.f);
        float v3 = fmaxf((m ? a1[3] : a0[3]) + bias1[m][3], 0.f);
        sv = uint2{pack2(v0, v1), pack2(v2, v3)};
      } else {
        sv = uint2{0u, 0u};
      }
      int chunk = (m * 2 + (lg >> 1)) ^ ((colb >> 1) & 3);
      char* dst = h1s + ((ry * 66 + colb) << 6) + (chunk << 4) + (lg & 1) * 8;
      *(uint2*)dst = sv;
    }
  };

  {
    bfrag c0, c1, n0, n1;
    ldfrag(wv * 10 + 0, c0, c1);
    #pragma unroll
    for (int i = 0; i < 10; ++i) {
      if (i < 9) ldfrag(wv * 10 + i + 1, n0, n1);
      comp(wv * 10 + i, c0, c1);
      c0 = n0; c1 = n1;
    }
  }
  __syncthreads();

  // W2 fragments from global, after the barrier (keeps Phase-A VGPR low).
  bfrag w2h[9], w2l[9];
  #pragma unroll
  for (int t = 0; t < 9; ++t) {
    const float* wp = w12 + lr * 288 + t;
    #pragma unroll
    for (int e = 0; e < 8; ++e) {
      float v = wp[(lg * 8 + e) * 9];
      w2h[t][e] = (short)bf_trunc(v);
      w2l[t][e] = (short)f2bf(v - bf_truncf(v));
    }
  }
  float bias2[4];
  #pragma unroll
  for (int r = 0; r < 4; ++r) bias2[r] = b12[lg * 4 + r];

  // ---- Phase B: conv2 (9 taps, K=32). 32 tiles (8 rows x 4), 8/wave.
  #pragma unroll 2
  for (int i = 0; i < 8; ++i) {
    const int nt   = wv * 8 + i;
    const int ryo  = nt >> 2;             // 0..7
    const int col0 = (nt & 3) << 4;
    ffrag acc = {0.f, 0.f, 0.f, 0.f};
    #pragma unroll
    for (int ky = 0; ky < 3; ++ky) {
      const int row = ryo + ky;
      #pragma unroll
      for (int kx = 0; kx < 3; ++kx) {
        const int colb  = col0 + lr + kx;
        const int chunk = lg ^ ((colb >> 1) & 3);
        const bfrag hv = *(const bfrag*)(h1s + ((row * 66 + colb) << 6) + (chunk << 4));
        acc = __builtin_amdgcn_mfma_f32_16x16x32_bf16(w2h[ky * 3 + kx], hv, acc, 0, 0, 0);
        acc = __builtin_amdgcn_mfma_f32_16x16x32_bf16(w2l[ky * 3 + kx], hv, acc, 0, 0, 0);
      }
    }
    const int px = (r0 + ryo) * WW + col0 + lr;
    uint2 o;
    o.x = packh2(fmaxf(acc[0] + bias2[0], 0.f), fmaxf(acc[1] + bias2[1], 0.f));
    o.y = packh2(fmaxf(acc[2] + bias2[2], 0.f), fmaxf(acc[3] + bias2[3], 0.f));
    *(uint2*)(h2 + ((size_t)blockIdx.y * HW + px) * 16 + lg * 4) = o;
  }
}

// ---------------------------------------------------------------------------
// K2: conv3 (1x1, 16->8, relu) + conv4 (3x3 pad1, 8->4, relu), fused (VALU).
// h2 fp16 NHWC -> h4 bf16 hi/lo planes [cb][8192] (FC flatten order).
// ---------------------------------------------------------------------------
__global__ __launch_bounds__(256) void k_conv34(
    const ushort* __restrict__ h2, const float* __restrict__ w21, const float* __restrict__ b21,
    const float* __restrict__ w22, const float* __restrict__ b22,
    ushort* __restrict__ h4h, ushort* __restrict__ h4l)
{
  __shared__ float h3s[18][64][9];
  __shared__ float __align__(16) w21s[128];
  __shared__ float __align__(16) w22s[288];
  const int tid = threadIdx.x;
  const int r0  = blockIdx.x * 16;
  const size_t b = blockIdx.y;

  for (int i = tid; i < 128; i += 256) w21s[(i & 15) * 8 + (i >> 4)] = w21[i];
  for (int i = tid; i < 288; i += 256) {
    int o = i / 72, r = i - o * 72, c = r / 9, tap = r - c * 9;
    w22s[(tap * 8 + c) * 4 + o] = w22[i];
  }
  __syncthreads();

  for (int p = tid; p < 18 * 64; p += 256) {
    const int ry = p >> 6, wc = p & 63;
    const int y  = r0 - 1 + ry;
    float* hd = &h3s[ry][wc][0];
    if (y >= 0 && y < HH) {
      const uint4* hp = (const uint4*)(h2 + ((b * HH + y) * WW + wc) * 16);
      uint4 ua = hp[0], ub = hp[1];
      uint32_t uw[8] = {ua.x, ua.y, ua.z, ua.w, ub.x, ub.y, ub.z, ub.w};
      float xv[16];
      #pragma unroll
      for (int j = 0; j < 8; ++j) {
        xv[2*j]   = h2f(uw[j] & 0xffffu);
        xv[2*j+1] = h2f(uw[j] >> 16);
      }
      float acc[C3];
      #pragma unroll
      for (int o = 0; o < C3; ++o) acc[o] = b21[o];
      #pragma unroll
      for (int c = 0; c < 16; ++c) {
        const float4* wr = (const float4*)&w21s[c * 8];
        float4 a = wr[0], d = wr[1];
        float v = xv[c];
        acc[0] = fmaf(v, a.x, acc[0]); acc[1] = fmaf(v, a.y, acc[1]);
        acc[2] = fmaf(v, a.z, acc[2]); acc[3] = fmaf(v, a.w, acc[3]);
        acc[4] = fmaf(v, d.x, acc[4]); acc[5] = fmaf(v, d.y, acc[5]);
        acc[6] = fmaf(v, d.z, acc[6]); acc[7] = fmaf(v, d.w, acc[7]);
      }
      #pragma unroll
      for (int c = 0; c < C3; ++c) hd[c] = fmaxf(acc[c], 0.f);
    } else {
      #pragma unroll
      for (int c = 0; c < C3; ++c) hd[c] = 0.f;
    }
  }
  __syncthreads();

  for (int p = tid; p < 1024; p += 256) {
    const int yl = p >> 6, wc = p & 63, ry = yl + 1;
    float acc[C4] = {b22[0], b22[1], b22[2], b22[3]};
    #pragma unroll
    for (int ky = 0; ky < 3; ++ky) {
      #pragma unroll
      for (int kx = 0; kx < 3; ++kx) {
        const int wcc = wc + kx - 1;
        if (wcc < 0 || wcc >= WW) continue;
        const float* hb = &h3s[ry + ky - 1][wcc][0];
        const int tap = ky * 3 + kx;
        #pragma unroll
        for (int c = 0; c < C3; ++c) {
          float v = hb[c];
          float4 w4 = *(const float4*)&w22s[(tap * 8 + c) * 4];
          acc[0] = fmaf(v, w4.x, acc[0]); acc[1] = fmaf(v, w4.y, acc[1]);
          acc[2] = fmaf(v, w4.z, acc[2]); acc[3] = fmaf(v, w4.w, acc[3]);
        }
      }
    }
    const size_t base = b * KFC + (r0 + yl) * WW + wc;
    #pragma unroll
    for (int o = 0; o < C4; ++o) {
      float v = fmaxf(acc[o], 0.f);
      h4h[base + (size_t)o * HW] = bf_trunc(v);
      h4l[base + (size_t)o * HW] = f2bf(v - bf_truncf(v));
    }
  }
}

// ---------------------------------------------------------------------------
// K2b: fcw fp32 -> bf16 hi/lo planes (once per launch, deterministic)
// ---------------------------------------------------------------------------
__global__ __launch_bounds__(256) void k_cvt_fcw(
    const float* __restrict__ w, ushort* __restrict__ hi, ushort* __restrict__ lo)
{
  const int i = (blockIdx.x * 256 + threadIdx.x) * 8;
  const float4 a = *(const float4*)(w + i);
  const float4 b = *(const float4*)(w + i + 4);
  uint4 hv, lv;
  hv.x = packhi2(a.x, a.y); hv.y = packhi2(a.z, a.w);
  hv.z = packhi2(b.x, b.y); hv.w = packhi2(b.z, b.w);
  lv.x = pack2(a.x - bf_truncf(a.x), a.y - bf_truncf(a.y));
  lv.y = pack2(a.z - bf_truncf(a.z), a.w - bf_truncf(a.w));
  lv.z = pack2(b.x - bf_truncf(b.x), b.y - bf_truncf(b.y));
  lv.w = pack2(b.z - bf_truncf(b.z), b.w - bf_truncf(b.w));
  *(uint4*)(hi + i) = hv;
  *(uint4*)(lo + i) = lv;
}

// ---------------------------------------------------------------------------
// K3: FC GEMM, MFMA bf16 3-product (hi/lo), K split KS-way, deterministic.
// ---------------------------------------------------------------------------
__global__ __launch_bounds__(256) void k_fc(
    const ushort* __restrict__ Ahp, const ushort* __restrict__ Alp,
    const ushort* __restrict__ Bhp, const ushort* __restrict__ Blp,
    float* __restrict__ zpart, int cb)
{
  const int tid = threadIdx.x;
  const int l   = tid & 63;
  const int wv  = tid >> 6;
  const int lr  = l & 15;
  const int lg  = l >> 4;
  const int m0  = blockIdx.x * 64 + (wv >> 1) * 32;
  const int n0  = blockIdx.y * 64 + (wv & 1) * 32;
  const int k0  = blockIdx.z * (KFC / KS);     // 512 per split

  int mrow[2], nrow[2];
  #pragma unroll
  for (int t = 0; t < 2; ++t) {
    int m = m0 + t * 16 + lr;
    mrow[t] = m < cb ? m : cb - 1;             // clamp; masked at write
    nrow[t] = n0 + t * 16 + lr;
  }
  ffrag acc[2][2] = {};

  #pragma unroll 1
  for (int kc = 0; kc < (KFC / KS) / 32; ++kc) {
    const int k = k0 + kc * 32 + lg * 8;
    bfrag ah[2], al[2], bh[2], bl[2];
    #pragma unroll
    for (int t = 0; t < 2; ++t) {
      ah[t] = *(const bfrag*)(Ahp + (size_t)mrow[t] * KFC + k);
      al[t] = *(const bfrag*)(Alp + (size_t)mrow[t] * KFC + k);
      bh[t] = *(const bfrag*)(Bhp + (size_t)nrow[t] * KFC + k);
      bl[t] = *(const bfrag*)(Blp + (size_t)nrow[t] * KFC + k);
    }
    #pragma unroll
    for (int mt = 0; mt < 2; ++mt) {
      #pragma unroll
      for (int nt = 0; nt < 2; ++nt) {
        acc[mt][nt] = __builtin_amdgcn_mfma_f32_16x16x32_bf16(ah[mt], bh[nt], acc[mt][nt], 0, 0, 0);
        acc[mt][nt] = __builtin_amdgcn_mfma_f32_16x16x32_bf16(ah[mt], bl[nt], acc[mt][nt], 0, 0, 0);
        acc[mt][nt] = __builtin_amdgcn_mfma_f32_16x16x32_bf16(al[mt], bh[nt], acc[mt][nt], 0, 0, 0);
      }
    }
  }

  #pragma unroll
  for (int mt = 0; mt < 2; ++mt) {
    #pragma unroll
    for (int r = 0; r < 4; ++r) {
      const int m = m0 + mt * 16 + lg * 4 + r;
      if (m < cb) {
        #pragma unroll
        for (int nt = 0; nt < 2; ++nt)
          zpart[((size_t)blockIdx.z * cb + m) * NOUT + n0 + nt * 16 + lr] = acc[mt][nt][r];
      }
    }
  }
}

// ---------------------------------------------------------------------------
// K5: fused coord + bilinear gather reading xt (NHWC bf16):
// per corner, 64 lanes read 64 consecutive channels = 128 B coalesced.
// ---------------------------------------------------------------------------
__global__ __launch_bounds__(256) void k_gather(
    const ushort* __restrict__ xt, const float* __restrict__ zpart,
    const float* __restrict__ fcb, float* __restrict__ out, int cb, int b0)
{
  const int bid = blockIdx.x;
  int bl, g;
  if ((cb & 7) == 0) {
    const int xcd = bid & 7;
    const int j   = bid >> 3;
    g  = j & 31;                 // 32 blocks per image
    bl = (j >> 5) * 8 + xcd;
  } else {
    bl = bid >> 5;
    g  = bid & 31;
  }
  const int node = g * 4 + (threadIdx.x >> 6);
  const int l    = threadIdx.x & 63;
  const int bg   = b0 + bl;

  float val = 0.f;
  if (l < 2 * KS) {
    const int kb = l >> 1, comp = l & 1;
    val = zpart[((size_t)kb * cb + bl) * NOUT + node * 2 + comp];
  }
  #pragma unroll
  for (int off = 2; off < 2 * KS; off <<= 1) val += __shfl_xor(val, off);
  const float z0 = __shfl(val, 0) + fcb[node * 2 + 0];
  const float z1 = __shfl(val, 1) + fcb[node * 2 + 1];
  const float ch = 31.f / (1.f + __expf(-3.f * z0));
  const float cw = 63.f / (1.f + __expf(-3.f * z1));

  if (l < 2)
    out[GF_SIZE + (((size_t)bg * NODES + node) << 1) + l] = l ? cw : ch;

  const float chv = fminf(fmaxf(ch, 0.f), 31.f);
  const float cwv = fminf(fmaxf(cw, 0.f), 63.f);
  const float fh = floorf(chv), fw = floorf(cwv);
  const int h0 = (int)fh, h1i = (int)ceilf(chv);
  const int w0 = (int)fw, w1i = (int)ceilf(cwv);
  const float oh = chv - fh, ow = cwv - fw;
  const ushort* xbp = xt + (size_t)bg * HW * CIN + l;
  const float v_lt = bf2f(xbp[(size_t)(h0 * WW + w0) * CIN]);
  const float v_rt = bf2f(xbp[(size_t)(h1i * WW + w0) * CIN]);
  const float v_lb = bf2f(xbp[(size_t)(h0 * WW + w1i) * CIN]);
  const float v_rb = bf2f(xbp[(size_t)(h1i * WW + w1i) * CIN]);
  const float vt = v_lt + oh * (v_rt - v_lt);
  const float vb = v_lb + oh * (v_rb - v_lb);
  out[((size_t)bg * NODES + node) * CIN + l] = vt + ow * (vb - vt);
}

// ---------------------------------------------------------------------------
extern "C" void kernel_launch(void* const* d_in, const int* in_sizes, int n_in,
                              void* d_out, int out_size, void* d_ws, size_t ws_size,
                              hipStream_t stream)
{
  (void)in_sizes; (void)n_in; (void)out_size;
  const float* x   = (const float*)d_in[0];
  const float* w11 = (const float*)d_in[1];
  const float* b11 = (const float*)d_in[2];
  const float* w12 = (const float*)d_in[3];
  const float* b12 = (const float*)d_in[4];
  const float* w21 = (const float*)d_in[5];
  const float* b21 = (const float*)d_in[6];
  const float* w22 = (const float*)d_in[7];
  const float* b22 = (const float*)d_in[8];
  const float* fcw = (const float*)d_in[9];
  const float* fcb = (const float*)d_in[10];
  float* out = (float*)d_out;
  char* wsb  = (char*)d_ws;

  // fixed: xt (134 MB) + fcw hi/lo planes (8 MB). ws_size ~= 1 GiB (measured
  // from the harness poison fill), so CB = 512 single chunk.
  const size_t xtBytes = (size_t)BATCH * HW * CIN * 2;
  const size_t perB    = 65536 + 16384 + 16384 + (size_t)KS * NOUT * 4;
  const size_t fixed   = xtBytes + 2 * 4194304;
  size_t avail = ws_size > fixed ? ws_size - fixed : perB;
  size_t cbmax = avail / perB;
  int CB = (int)(cbmax < (size_t)BATCH ? cbmax : (size_t)BATCH);
  if (CB < 1) CB = 1;

  char* p = wsb;
  ushort* xtv  = (ushort*)p;  p += xtBytes;
  ushort* h2v  = (ushort*)p;  p += (size_t)CB * 65536;
  ushort* h4h  = (ushort*)p;  p += (size_t)CB * 16384;
  ushort* h4l  = (ushort*)p;  p += (size_t)CB * 16384;
  float*  zpv  = (float*)p;   p += (size_t)CB * KS * NOUT * 4;
  ushort* fcwh = (ushort*)p;  p += 4194304;
  ushort* fcwl = (ushort*)p;

  k_cvt_fcw<<<dim3(NOUT * KFC / (256 * 8)), 256, 0, stream>>>(fcw, fcwh, fcwl);
  k_xpose<<<dim3(8, BATCH), 256, 0, stream>>>(x, xtv);

  for (int b0 = 0; b0 < BATCH; b0 += CB) {
    const int cb = (BATCH - b0 < CB) ? (BATCH - b0) : CB;
    k_conv12<<<dim3(4, cb), 256, 0, stream>>>(xtv, w11, b11, w12, b12, h2v, b0);
    k_conv34<<<dim3(2, cb), 256, 0, stream>>>(h2v, w21, b21, w22, b22, h4h, h4l);
    k_fc<<<dim3((cb + 63) / 64, 4, KS), 256, 0, stream>>>(h4h, h4l, fcwh, fcwl, zpv, cb);
    k_gather<<<dim3(cb * 32), 256, 0, stream>>>(xtv, zpv, fcb, out, cb, b0);
  }
}

// Round 9
// 234.782 us; speedup vs baseline: 1.5017x; 1.1851x over previous
//
#include <hip/hip_runtime.h>
#include <hip/hip_fp16.h>
#include <cstdint>

#define BATCH 512
#define CIN   64
#define HH    32
#define WW    64
#define HW    2048
#define C1    32
#define C2    16
#define C3    8
#define C4    4
#define NOUT  256
#define KFC   8192
#define NODES 128
#define KS    16                      // FC K-split
#define GF_SIZE (BATCH * NODES * CIN)

typedef __attribute__((ext_vector_type(8))) short bfrag;   // 8 bf16 (4 VGPRs)
typedef __attribute__((ext_vector_type(4))) float ffrag;   // 4 fp32 acc

__device__ __forceinline__ ushort bf_trunc(float f) { return (ushort)(__float_as_uint(f) >> 16); }
__device__ __forceinline__ float  bf_truncf(float f) { return __uint_as_float(__float_as_uint(f) & 0xffff0000u); }
__device__ __forceinline__ ushort f2bf(float f) {
  uint32_t u = __float_as_uint(f);
  return (ushort)((u + 0x7fffu + ((u >> 16) & 1u)) >> 16);
}
__device__ __forceinline__ uint32_t pack2(float a, float b) {
  return (uint32_t)f2bf(a) | ((uint32_t)f2bf(b) << 16);
}
__device__ __forceinline__ uint32_t packhi2(float a, float b) {
  return (uint32_t)bf_trunc(a) | ((uint32_t)bf_trunc(b) << 16);
}
__device__ __forceinline__ ushort f2h(float f) { return __half_as_ushort(__float2half_rn(f)); }
__device__ __forceinline__ uint32_t packh2(float a, float b) {
  return (uint32_t)f2h(a) | ((uint32_t)f2h(b) << 16);
}
__device__ __forceinline__ float h2f(uint32_t u) { return __half2float(__ushort_as_half((ushort)u)); }
__device__ __forceinline__ float bf2f(ushort u) { return __uint_as_float(((uint32_t)u) << 16); }

// ---------------------------------------------------------------------------
// K0: x NCHW fp32 -> xt NHWC bf16 (RTN), LDS-staged for coalesced stores.
// Round-9 fix: R8's direct stores were 16 B/lane at 128-B stride (64
// discontiguous segments per wave instruction -> transaction-limited,
// 1.9 TB/s). Now: reads coalesced (256 thr x dword along px, 64 ch iters,
// bf16-pair packed into LDS [256 px][33 u32] pad -> 2-way = free); store
// phase writes consecutive uint4 per consecutive lane = 4 KB/wave-inst.
// grid (8, BATCH), block 256; block = (image, 4 rows).
// ---------------------------------------------------------------------------
__global__ __launch_bounds__(256) void k_xpose(
    const float* __restrict__ x, ushort* __restrict__ xt)
{
  __shared__ uint32_t tb[256 * 33];
  const int t  = threadIdx.x;
  const int b  = blockIdx.y;
  const int rg = blockIdx.x;                 // 4-row group, 256 px
  const float* xp = x + (size_t)b * CIN * HW + rg * 256 + t;
  #pragma unroll
  for (int j = 0; j < 32; ++j) {
    float v0 = xp[(size_t)(2 * j) * HW];
    float v1 = xp[(size_t)(2 * j + 1) * HW];
    tb[t * 33 + j] = pack2(v0, v1);
  }
  __syncthreads();
  ushort* op = xt + ((size_t)b * HW + rg * 256) * CIN;
  #pragma unroll
  for (int k = 0; k < 8; ++k) {
    const int u = k * 256 + t;               // uint4 index in the 32 KB tile
    const int p = u >> 3, q = u & 7;         // pixel, 8-ch chunk
    uint4 v;
    v.x = tb[p * 33 + q * 4 + 0];
    v.y = tb[p * 33 + q * 4 + 1];
    v.z = tb[p * 33 + q * 4 + 2];
    v.w = tb[p * 33 + q * 4 + 3];
    *(uint4*)(op + (size_t)u * 8) = v;
  }
}

// ---------------------------------------------------------------------------
// K1: conv1 (1x1, 64->32) + conv2 (3x3 pad1, 32->16) fused, MFMA bf16.
// Consumes xt (NHWC bf16); Phase A per tile = two coalesced 16 B loads,
// zero convert VALU, 2-deep frag prefetch. Weights hi/lo split (fp32-grade).
// LDS = h1 [10][66][64B] = 42240 B -> 3 blocks/CU. No launch_bounds min-occ
// arg (R3/R7 lesson: it forces spill).
// xt NHWC bf16 -> h2 fp16 NHWC [cb][32][64][16].  grid (4, cb), 256 thr.
// ---------------------------------------------------------------------------
__global__ __launch_bounds__(256) void k_conv12(
    const ushort* __restrict__ xt, const float* __restrict__ w11, const float* __restrict__ b11,
    const float* __restrict__ w12, const float* __restrict__ b12,
    ushort* __restrict__ h2, int b0)
{
  __shared__ __align__(16) char h1s[10 * 66 * 64];   // 42240 B
  const int tid = threadIdx.x;
  const int l   = tid & 63;
  const int wv  = tid >> 6;    // 0..3
  const int lr  = l & 15;
  const int lg  = l >> 4;
  const int r0  = blockIdx.x * 8;
  const int bg  = b0 + blockIdx.y;
  const ushort* xtb = xt + (size_t)bg * HW * CIN;

  // zero the padded columns (colb = 0 and 65) of all 10 rows
  if (tid < 160) {
    int row = tid >> 4, half = (tid >> 3) & 1, q = tid & 7;
    int cell = row * 66 + (half ? 65 : 0);
    *(uint2*)(h1s + (cell << 6) + q * 8) = uint2{0u, 0u};
  }

  // W1 fragments from global (hi/lo split keeps W fp32-grade)
  bfrag w1h[2][2], w1l[2][2];   // [Mtile][kstep]
  #pragma unroll
  for (int m = 0; m < 2; ++m) {
    #pragma unroll
    for (int ks = 0; ks < 2; ++ks) {
      const float* wp = w11 + (m * 16 + lr) * 64 + ks * 32 + lg * 8;
      #pragma unroll
      for (int e = 0; e < 8; ++e) {
        float v = wp[e];
        w1h[m][ks][e] = (short)bf_trunc(v);
        w1l[m][ks][e] = (short)f2bf(v - bf_truncf(v));
      }
    }
  }
  float bias1[2][4];
  #pragma unroll
  for (int m = 0; m < 2; ++m) {
    #pragma unroll
    for (int r = 0; r < 4; ++r) bias1[m][r] = b11[m * 16 + lg * 4 + r];
  }

  // ---- Phase A: conv1 -> h1 LDS. 40 tiles (10 rows x 4 col-tiles), 10/wave,
  // 2-deep fragment prefetch; loads are coalesced dwordx4 from xt.
  auto ldfrag = [&](int nt, bfrag& f0, bfrag& f1) {
    const int ry = nt >> 2, col0 = (nt & 3) << 4;
    const int y  = r0 - 1 + ry;
    if (y >= 0 && y < HH) {
      const ushort* xp = xtb + (size_t)(y * WW + col0 + lr) * CIN + lg * 8;
      f0 = *(const bfrag*)xp;
      f1 = *(const bfrag*)(xp + 32);
    } else {
      #pragma unroll
      for (int e = 0; e < 8; ++e) { f0[e] = 0; f1[e] = 0; }
    }
  };
  auto comp = [&](int nt, bfrag f0, bfrag f1) {
    const int ry = nt >> 2, col0 = (nt & 3) << 4;
    const int y  = r0 - 1 + ry;
    const bool valid = (y >= 0) && (y < HH);
    const int colb = col0 + 1 + lr;
    ffrag a0 = {0.f, 0.f, 0.f, 0.f}, a1 = {0.f, 0.f, 0.f, 0.f};
    a0 = __builtin_amdgcn_mfma_f32_16x16x32_bf16(w1h[0][0], f0, a0, 0, 0, 0);
    a0 = __builtin_amdgcn_mfma_f32_16x16x32_bf16(w1l[0][0], f0, a0, 0, 0, 0);
    a0 = __builtin_amdgcn_mfma_f32_16x16x32_bf16(w1h[0][1], f1, a0, 0, 0, 0);
    a0 = __builtin_amdgcn_mfma_f32_16x16x32_bf16(w1l[0][1], f1, a0, 0, 0, 0);
    a1 = __builtin_amdgcn_mfma_f32_16x16x32_bf16(w1h[1][0], f0, a1, 0, 0, 0);
    a1 = __builtin_amdgcn_mfma_f32_16x16x32_bf16(w1l[1][0], f0, a1, 0, 0, 0);
    a1 = __builtin_amdgcn_mfma_f32_16x16x32_bf16(w1h[1][1], f1, a1, 0, 0, 0);
    a1 = __builtin_amdgcn_mfma_f32_16x16x32_bf16(w1l[1][1], f1, a1, 0, 0, 0);
    #pragma unroll
    for (int m = 0; m < 2; ++m) {
      uint2 sv;
      if (valid) {
        float v0 = fmaxf((m ? a1[0] : a0[0]) + bias1[m][0], 0.f);
        float v1 = fmaxf((m ? a1[1] : a0[1]) + bias1[m][1], 0.f);
        float v2 = fmaxf((m ? a1[2] : a0[2]) + bias1[m][2], 0.f);
        float v3 = fmaxf((m ? a1[3] : a0[3]) + bias1[m][3], 0.f);
        sv = uint2{pack2(v0, v1), pack2(v2, v3)};
      } else {
        sv = uint2{0u, 0u};
      }
      int chunk = (m * 2 + (lg >> 1)) ^ ((colb >> 1) & 3);
      char* dst = h1s + ((ry * 66 + colb) << 6) + (chunk << 4) + (lg & 1) * 8;
      *(uint2*)dst = sv;
    }
  };

  {
    bfrag c0, c1, n0, n1;
    ldfrag(wv * 10 + 0, c0, c1);
    #pragma unroll
    for (int i = 0; i < 10; ++i) {
      if (i < 9) ldfrag(wv * 10 + i + 1, n0, n1);
      comp(wv * 10 + i, c0, c1);
      c0 = n0; c1 = n1;
    }
  }
  __syncthreads();

  // W2 fragments from global, after the barrier (keeps Phase-A VGPR low).
  bfrag w2h[9], w2l[9];
  #pragma unroll
  for (int t = 0; t < 9; ++t) {
    const float* wp = w12 + lr * 288 + t;
    #pragma unroll
    for (int e = 0; e < 8; ++e) {
      float v = wp[(lg * 8 + e) * 9];
      w2h[t][e] = (short)bf_trunc(v);
      w2l[t][e] = (short)f2bf(v - bf_truncf(v));
    }
  }
  float bias2[4];
  #pragma unroll
  for (int r = 0; r < 4; ++r) bias2[r] = b12[lg * 4 + r];

  // ---- Phase B: conv2 (9 taps, K=32). 32 tiles (8 rows x 4), 8/wave.
  #pragma unroll 2
  for (int i = 0; i < 8; ++i) {
    const int nt   = wv * 8 + i;
    const int ryo  = nt >> 2;             // 0..7
    const int col0 = (nt & 3) << 4;
    ffrag acc = {0.f, 0.f, 0.f, 0.f};
    #pragma unroll
    for (int ky = 0; ky < 3; ++ky) {
      const int row = ryo + ky;
      #pragma unroll
      for (int kx = 0; kx < 3; ++kx) {
        const int colb  = col0 + lr + kx;
        const int chunk = lg ^ ((colb >> 1) & 3);
        const bfrag hv = *(const bfrag*)(h1s + ((row * 66 + colb) << 6) + (chunk << 4));
        acc = __builtin_amdgcn_mfma_f32_16x16x32_bf16(w2h[ky * 3 + kx], hv, acc, 0, 0, 0);
        acc = __builtin_amdgcn_mfma_f32_16x16x32_bf16(w2l[ky * 3 + kx], hv, acc, 0, 0, 0);
      }
    }
    const int px = (r0 + ryo) * WW + col0 + lr;
    uint2 o;
    o.x = packh2(fmaxf(acc[0] + bias2[0], 0.f), fmaxf(acc[1] + bias2[1], 0.f));
    o.y = packh2(fmaxf(acc[2] + bias2[2], 0.f), fmaxf(acc[3] + bias2[3], 0.f));
    *(uint2*)(h2 + ((size_t)blockIdx.y * HW + px) * 16 + lg * 4) = o;
  }
}

// ---------------------------------------------------------------------------
// K2: conv3 (1x1, 16->8, relu) + conv4 (3x3 pad1, 8->4, relu), fused (VALU).
// h2 fp16 NHWC -> h4 bf16 hi/lo planes [cb][8192] (FC flatten order).
// ---------------------------------------------------------------------------
__global__ __launch_bounds__(256) void k_conv34(
    const ushort* __restrict__ h2, const float* __restrict__ w21, const float* __restrict__ b21,
    const float* __restrict__ w22, const float* __restrict__ b22,
    ushort* __restrict__ h4h, ushort* __restrict__ h4l)
{
  __shared__ float h3s[18][64][9];
  __shared__ float __align__(16) w21s[128];
  __shared__ float __align__(16) w22s[288];
  const int tid = threadIdx.x;
  const int r0  = blockIdx.x * 16;
  const size_t b = blockIdx.y;

  for (int i = tid; i < 128; i += 256) w21s[(i & 15) * 8 + (i >> 4)] = w21[i];
  for (int i = tid; i < 288; i += 256) {
    int o = i / 72, r = i - o * 72, c = r / 9, tap = r - c * 9;
    w22s[(tap * 8 + c) * 4 + o] = w22[i];
  }
  __syncthreads();

  for (int p = tid; p < 18 * 64; p += 256) {
    const int ry = p >> 6, wc = p & 63;
    const int y  = r0 - 1 + ry;
    float* hd = &h3s[ry][wc][0];
    if (y >= 0 && y < HH) {
      const uint4* hp = (const uint4*)(h2 + ((b * HH + y) * WW + wc) * 16);
      uint4 ua = hp[0], ub = hp[1];
      uint32_t uw[8] = {ua.x, ua.y, ua.z, ua.w, ub.x, ub.y, ub.z, ub.w};
      float xv[16];
      #pragma unroll
      for (int j = 0; j < 8; ++j) {
        xv[2*j]   = h2f(uw[j] & 0xffffu);
        xv[2*j+1] = h2f(uw[j] >> 16);
      }
      float acc[C3];
      #pragma unroll
      for (int o = 0; o < C3; ++o) acc[o] = b21[o];
      #pragma unroll
      for (int c = 0; c < 16; ++c) {
        const float4* wr = (const float4*)&w21s[c * 8];
        float4 a = wr[0], d = wr[1];
        float v = xv[c];
        acc[0] = fmaf(v, a.x, acc[0]); acc[1] = fmaf(v, a.y, acc[1]);
        acc[2] = fmaf(v, a.z, acc[2]); acc[3] = fmaf(v, a.w, acc[3]);
        acc[4] = fmaf(v, d.x, acc[4]); acc[5] = fmaf(v, d.y, acc[5]);
        acc[6] = fmaf(v, d.z, acc[6]); acc[7] = fmaf(v, d.w, acc[7]);
      }
      #pragma unroll
      for (int c = 0; c < C3; ++c) hd[c] = fmaxf(acc[c], 0.f);
    } else {
      #pragma unroll
      for (int c = 0; c < C3; ++c) hd[c] = 0.f;
    }
  }
  __syncthreads();

  for (int p = tid; p < 1024; p += 256) {
    const int yl = p >> 6, wc = p & 63, ry = yl + 1;
    float acc[C4] = {b22[0], b22[1], b22[2], b22[3]};
    #pragma unroll
    for (int ky = 0; ky < 3; ++ky) {
      #pragma unroll
      for (int kx = 0; kx < 3; ++kx) {
        const int wcc = wc + kx - 1;
        if (wcc < 0 || wcc >= WW) continue;
        const float* hb = &h3s[ry + ky - 1][wcc][0];
        const int tap = ky * 3 + kx;
        #pragma unroll
        for (int c = 0; c < C3; ++c) {
          float v = hb[c];
          float4 w4 = *(const float4*)&w22s[(tap * 8 + c) * 4];
          acc[0] = fmaf(v, w4.x, acc[0]); acc[1] = fmaf(v, w4.y, acc[1]);
          acc[2] = fmaf(v, w4.z, acc[2]); acc[3] = fmaf(v, w4.w, acc[3]);
        }
      }
    }
    const size_t base = b * KFC + (r0 + yl) * WW + wc;
    #pragma unroll
    for (int o = 0; o < C4; ++o) {
      float v = fmaxf(acc[o], 0.f);
      h4h[base + (size_t)o * HW] = bf_trunc(v);
      h4l[base + (size_t)o * HW] = f2bf(v - bf_truncf(v));
    }
  }
}

// ---------------------------------------------------------------------------
// K2b: fcw fp32 -> bf16 hi/lo planes (once per launch, deterministic)
// ---------------------------------------------------------------------------
__global__ __launch_bounds__(256) void k_cvt_fcw(
    const float* __restrict__ w, ushort* __restrict__ hi, ushort* __restrict__ lo)
{
  const int i = (blockIdx.x * 256 + threadIdx.x) * 8;
  const float4 a = *(const float4*)(w + i);
  const float4 b = *(const float4*)(w + i + 4);
  uint4 hv, lv;
  hv.x = packhi2(a.x, a.y); hv.y = packhi2(a.z, a.w);
  hv.z = packhi2(b.x, b.y); hv.w = packhi2(b.z, b.w);
  lv.x = pack2(a.x - bf_truncf(a.x), a.y - bf_truncf(a.y));
  lv.y = pack2(a.z - bf_truncf(a.z), a.w - bf_truncf(a.w));
  lv.z = pack2(b.x - bf_truncf(b.x), b.y - bf_truncf(b.y));
  lv.w = pack2(b.z - bf_truncf(b.z), b.w - bf_truncf(b.w));
  *(uint4*)(hi + i) = hv;
  *(uint4*)(lo + i) = lv;
}

// ---------------------------------------------------------------------------
// K3: FC GEMM, MFMA bf16 3-product (hi/lo), K split KS-way, deterministic.
// ---------------------------------------------------------------------------
__global__ __launch_bounds__(256) void k_fc(
    const ushort* __restrict__ Ahp, const ushort* __restrict__ Alp,
    const ushort* __restrict__ Bhp, const ushort* __restrict__ Blp,
    float* __restrict__ zpart, int cb)
{
  const int tid = threadIdx.x;
  const int l   = tid & 63;
  const int wv  = tid >> 6;
  const int lr  = l & 15;
  const int lg  = l >> 4;
  const int m0  = blockIdx.x * 64 + (wv >> 1) * 32;
  const int n0  = blockIdx.y * 64 + (wv & 1) * 32;
  const int k0  = blockIdx.z * (KFC / KS);     // 512 per split

  int mrow[2], nrow[2];
  #pragma unroll
  for (int t = 0; t < 2; ++t) {
    int m = m0 + t * 16 + lr;
    mrow[t] = m < cb ? m : cb - 1;             // clamp; masked at write
    nrow[t] = n0 + t * 16 + lr;
  }
  ffrag acc[2][2] = {};

  #pragma unroll 1
  for (int kc = 0; kc < (KFC / KS) / 32; ++kc) {
    const int k = k0 + kc * 32 + lg * 8;
    bfrag ah[2], al[2], bh[2], bl[2];
    #pragma unroll
    for (int t = 0; t < 2; ++t) {
      ah[t] = *(const bfrag*)(Ahp + (size_t)mrow[t] * KFC + k);
      al[t] = *(const bfrag*)(Alp + (size_t)mrow[t] * KFC + k);
      bh[t] = *(const bfrag*)(Bhp + (size_t)nrow[t] * KFC + k);
      bl[t] = *(const bfrag*)(Blp + (size_t)nrow[t] * KFC + k);
    }
    #pragma unroll
    for (int mt = 0; mt < 2; ++mt) {
      #pragma unroll
      for (int nt = 0; nt < 2; ++nt) {
        acc[mt][nt] = __builtin_amdgcn_mfma_f32_16x16x32_bf16(ah[mt], bh[nt], acc[mt][nt], 0, 0, 0);
        acc[mt][nt] = __builtin_amdgcn_mfma_f32_16x16x32_bf16(ah[mt], bl[nt], acc[mt][nt], 0, 0, 0);
        acc[mt][nt] = __builtin_amdgcn_mfma_f32_16x16x32_bf16(al[mt], bh[nt], acc[mt][nt], 0, 0, 0);
      }
    }
  }

  #pragma unroll
  for (int mt = 0; mt < 2; ++mt) {
    #pragma unroll
    for (int r = 0; r < 4; ++r) {
      const int m = m0 + mt * 16 + lg * 4 + r;
      if (m < cb) {
        #pragma unroll
        for (int nt = 0; nt < 2; ++nt)
          zpart[((size_t)blockIdx.z * cb + m) * NOUT + n0 + nt * 16 + lr] = acc[mt][nt][r];
      }
    }
  }
}

// ---------------------------------------------------------------------------
// K5: fused coord + bilinear gather reading xt (NHWC bf16):
// per corner, 64 lanes read 64 consecutive channels = 128 B coalesced.
// ---------------------------------------------------------------------------
__global__ __launch_bounds__(256) void k_gather(
    const ushort* __restrict__ xt, const float* __restrict__ zpart,
    const float* __restrict__ fcb, float* __restrict__ out, int cb, int b0)
{
  const int bid = blockIdx.x;
  int bl, g;
  if ((cb & 7) == 0) {
    const int xcd = bid & 7;
    const int j   = bid >> 3;
    g  = j & 31;                 // 32 blocks per image
    bl = (j >> 5) * 8 + xcd;
  } else {
    bl = bid >> 5;
    g  = bid & 31;
  }
  const int node = g * 4 + (threadIdx.x >> 6);
  const int l    = threadIdx.x & 63;
  const int bg   = b0 + bl;

  float val = 0.f;
  if (l < 2 * KS) {
    const int kb = l >> 1, comp = l & 1;
    val = zpart[((size_t)kb * cb + bl) * NOUT + node * 2 + comp];
  }
  #pragma unroll
  for (int off = 2; off < 2 * KS; off <<= 1) val += __shfl_xor(val, off);
  const float z0 = __shfl(val, 0) + fcb[node * 2 + 0];
  const float z1 = __shfl(val, 1) + fcb[node * 2 + 1];
  const float ch = 31.f / (1.f + __expf(-3.f * z0));
  const float cw = 63.f / (1.f + __expf(-3.f * z1));

  if (l < 2)
    out[GF_SIZE + (((size_t)bg * NODES + node) << 1) + l] = l ? cw : ch;

  const float chv = fminf(fmaxf(ch, 0.f), 31.f);
  const float cwv = fminf(fmaxf(cw, 0.f), 63.f);
  const float fh = floorf(chv), fw = floorf(cwv);
  const int h0 = (int)fh, h1i = (int)ceilf(chv);
  const int w0 = (int)fw, w1i = (int)ceilf(cwv);
  const float oh = chv - fh, ow = cwv - fw;
  const ushort* xbp = xt + (size_t)bg * HW * CIN + l;
  const float v_lt = bf2f(xbp[(size_t)(h0 * WW + w0) * CIN]);
  const float v_rt = bf2f(xbp[(size_t)(h1i * WW + w0) * CIN]);
  const float v_lb = bf2f(xbp[(size_t)(h0 * WW + w1i) * CIN]);
  const float v_rb = bf2f(xbp[(size_t)(h1i * WW + w1i) * CIN]);
  const float vt = v_lt + oh * (v_rt - v_lt);
  const float vb = v_lb + oh * (v_rb - v_lb);
  out[((size_t)bg * NODES + node) * CIN + l] = vt + ow * (vb - vt);
}

// ---------------------------------------------------------------------------
extern "C" void kernel_launch(void* const* d_in, const int* in_sizes, int n_in,
                              void* d_out, int out_size, void* d_ws, size_t ws_size,
                              hipStream_t stream)
{
  (void)in_sizes; (void)n_in; (void)out_size;
  const float* x   = (const float*)d_in[0];
  const float* w11 = (const float*)d_in[1];
  const float* b11 = (const float*)d_in[2];
  const float* w12 = (const float*)d_in[3];
  const float* b12 = (const float*)d_in[4];
  const float* w21 = (const float*)d_in[5];
  const float* b21 = (const float*)d_in[6];
  const float* w22 = (const float*)d_in[7];
  const float* b22 = (const float*)d_in[8];
  const float* fcw = (const float*)d_in[9];
  const float* fcb = (const float*)d_in[10];
  float* out = (float*)d_out;
  char* wsb  = (char*)d_ws;

  // fixed: xt (134 MB) + fcw hi/lo planes (8 MB). ws_size ~= 1 GiB.
  const size_t xtBytes = (size_t)BATCH * HW * CIN * 2;
  const size_t perB    = 65536 + 16384 + 16384 + (size_t)KS * NOUT * 4;
  const size_t fixed   = xtBytes + 2 * 4194304;
  size_t avail = ws_size > fixed ? ws_size - fixed : perB;
  size_t cbmax = avail / perB;
  int CB = (int)(cbmax < (size_t)BATCH ? cbmax : (size_t)BATCH);
  if (CB < 1) CB = 1;

  char* p = wsb;
  ushort* xtv  = (ushort*)p;  p += xtBytes;
  ushort* h2v  = (ushort*)p;  p += (size_t)CB * 65536;
  ushort* h4h  = (ushort*)p;  p += (size_t)CB * 16384;
  ushort* h4l  = (ushort*)p;  p += (size_t)CB * 16384;
  float*  zpv  = (float*)p;   p += (size_t)CB * KS * NOUT * 4;
  ushort* fcwh = (ushort*)p;  p += 4194304;
  ushort* fcwl = (ushort*)p;

  k_cvt_fcw<<<dim3(NOUT * KFC / (256 * 8)), 256, 0, stream>>>(fcw, fcwh, fcwl);
  k_xpose<<<dim3(8, BATCH), 256, 0, stream>>>(x, xtv);

  for (int b0 = 0; b0 < BATCH; b0 += CB) {
    const int cb = (BATCH - b0 < CB) ? (BATCH - b0) : CB;
    k_conv12<<<dim3(4, cb), 256, 0, stream>>>(xtv, w11, b11, w12, b12, h2v, b0);
    k_conv34<<<dim3(2, cb), 256, 0, stream>>>(h2v, w21, b21, w22, b22, h4h, h4l);
    k_fc<<<dim3((cb + 63) / 64, 4, KS), 256, 0, stream>>>(h4h, h4l, fcwh, fcwl, zpv, cb);
    k_gather<<<dim3(cb * 32), 256, 0, stream>>>(xtv, zpv, fcb, out, cb, b0);
  }
}

// Round 10
// 225.197 us; speedup vs baseline: 1.5656x; 1.0426x over previous
//
#include <hip/hip_runtime.h>
#include <hip/hip_fp16.h>
#include <cstdint>

#define BATCH 512
#define CIN   64
#define HH    32
#define WW    64
#define HW    2048
#define C1    32
#define C2    16
#define C3    8
#define C4    4
#define NOUT  256
#define KFC   8192
#define NODES 128
#define KS    16                      // FC K-split
#define GF_SIZE (BATCH * NODES * CIN)

typedef __attribute__((ext_vector_type(8))) short bfrag;   // 8 bf16 (4 VGPRs)
typedef __attribute__((ext_vector_type(4))) float ffrag;   // 4 fp32 acc

__device__ __forceinline__ ushort bf_trunc(float f) { return (ushort)(__float_as_uint(f) >> 16); }
__device__ __forceinline__ float  bf_truncf(float f) { return __uint_as_float(__float_as_uint(f) & 0xffff0000u); }
__device__ __forceinline__ ushort f2bf(float f) {
  uint32_t u = __float_as_uint(f);
  return (ushort)((u + 0x7fffu + ((u >> 16) & 1u)) >> 16);
}
__device__ __forceinline__ uint32_t pack2(float a, float b) {
  return (uint32_t)f2bf(a) | ((uint32_t)f2bf(b) << 16);
}
__device__ __forceinline__ uint32_t packhi2(float a, float b) {
  return (uint32_t)bf_trunc(a) | ((uint32_t)bf_trunc(b) << 16);
}
__device__ __forceinline__ ushort f2h(float f) { return __half_as_ushort(__float2half_rn(f)); }
__device__ __forceinline__ uint32_t packh2(float a, float b) {
  return (uint32_t)f2h(a) | ((uint32_t)f2h(b) << 16);
}
__device__ __forceinline__ float h2f(uint32_t u) { return __half2float(__ushort_as_half((ushort)u)); }
__device__ __forceinline__ float bf2f(ushort u) { return __uint_as_float(((uint32_t)u) << 16); }

// ---------------------------------------------------------------------------
// K0: x NCHW fp32 -> xt NHWC bf16 (RTN), LDS-staged for coalesced stores.
// (R9 proven: reads coalesced along px; stores 4 KB contiguous per wave.)
// ---------------------------------------------------------------------------
__global__ __launch_bounds__(256) void k_xpose(
    const float* __restrict__ x, ushort* __restrict__ xt)
{
  __shared__ uint32_t tb[256 * 33];
  const int t  = threadIdx.x;
  const int b  = blockIdx.y;
  const int rg = blockIdx.x;                 // 4-row group, 256 px
  const float* xp = x + (size_t)b * CIN * HW + rg * 256 + t;
  #pragma unroll
  for (int j = 0; j < 32; ++j) {
    float v0 = xp[(size_t)(2 * j) * HW];
    float v1 = xp[(size_t)(2 * j + 1) * HW];
    tb[t * 33 + j] = pack2(v0, v1);
  }
  __syncthreads();
  ushort* op = xt + ((size_t)b * HW + rg * 256) * CIN;
  #pragma unroll
  for (int k = 0; k < 8; ++k) {
    const int u = k * 256 + t;
    const int p = u >> 3, q = u & 7;
    uint4 v;
    v.x = tb[p * 33 + q * 4 + 0];
    v.y = tb[p * 33 + q * 4 + 1];
    v.z = tb[p * 33 + q * 4 + 2];
    v.w = tb[p * 33 + q * 4 + 3];
    *(uint4*)(op + (size_t)u * 8) = v;
  }
}

// ---------------------------------------------------------------------------
// K1: conv1+conv2+conv3+conv4 fully fused. Round-10: conv34 folded in.
//  Phase A: conv1 (MFMA, W fp32-grade hi/lo) -> h1 bf16 LDS, 12 rows
//           (rows r0-2..r0+9; 1.5x halo).              LDS 12*66*64=50688 B
//  Phase B: conv2 (MFMA, 9 taps) -> h2 fp16 rows r0-1..r0+8 in REGISTERS
//           (10 tiles/wave, 2 packed u32 each = 20 VGPR).
//  barrier; h2 regs -> LDS (reuse h1 space, [10][64][32B fp16]);
//  Phase C1: conv3 (VALU, scalar-load weights) -> h3 fp32 LDS [10][64][9].
//  Phase C2: conv4 (VALU) -> h4 bf16 hi/lo global (FC flatten order).
// h2 never touches HBM; conv34 kernel + launch gap eliminated.
// 3 blocks/CU (50.7 KB LDS). No launch_bounds min-occ arg (R3/R7 lesson).
// grid (4, cb), 256 thr.
// ---------------------------------------------------------------------------
__global__ __launch_bounds__(256) void k_conv1234(
    const ushort* __restrict__ xt, const float* __restrict__ w11, const float* __restrict__ b11,
    const float* __restrict__ w12, const float* __restrict__ b12,
    const float* __restrict__ w21, const float* __restrict__ b21,
    const float* __restrict__ w22, const float* __restrict__ b22,
    ushort* __restrict__ h4h, ushort* __restrict__ h4l, int b0)
{
  __shared__ __align__(16) char smem[12 * 66 * 64];   // 50688 B
  const int tid = threadIdx.x;
  const int l   = tid & 63;
  const int wv  = tid >> 6;    // 0..3
  const int lr  = l & 15;
  const int lg  = l >> 4;
  const int r0  = blockIdx.x * 8;
  const int bg  = b0 + blockIdx.y;
  const ushort* xtb = xt + (size_t)bg * HW * CIN;

  // zero padded cols (colb 0 and 65) of all 12 h1 rows
  if (tid < 192) {
    int cell = tid >> 3, q = tid & 7;
    int row = cell >> 1, colb = (cell & 1) ? 65 : 0;
    *(uint2*)(smem + ((row * 66 + colb) << 6) + q * 8) = uint2{0u, 0u};
  }

  // W1 fragments from global (hi/lo split keeps W fp32-grade)
  bfrag w1h[2][2], w1l[2][2];
  #pragma unroll
  for (int m = 0; m < 2; ++m) {
    #pragma unroll
    for (int ks = 0; ks < 2; ++ks) {
      const float* wp = w11 + (m * 16 + lr) * 64 + ks * 32 + lg * 8;
      #pragma unroll
      for (int e = 0; e < 8; ++e) {
        float v = wp[e];
        w1h[m][ks][e] = (short)bf_trunc(v);
        w1l[m][ks][e] = (short)f2bf(v - bf_truncf(v));
      }
    }
  }
  float bias1[2][4];
  #pragma unroll
  for (int m = 0; m < 2; ++m) {
    #pragma unroll
    for (int r = 0; r < 4; ++r) bias1[m][r] = b11[m * 16 + lg * 4 + r];
  }

  // ---- Phase A: conv1 -> h1 LDS. 48 tiles (12 rows x 4 col-tiles), 12/wave,
  // 2-deep fragment prefetch; coalesced dwordx4 loads from xt.
  auto ldfrag = [&](int nt, bfrag& f0, bfrag& f1) {
    const int ry = nt >> 2, col0 = (nt & 3) << 4;
    const int y  = r0 - 2 + ry;
    if (y >= 0 && y < HH) {
      const ushort* xp = xtb + (size_t)(y * WW + col0 + lr) * CIN + lg * 8;
      f0 = *(const bfrag*)xp;
      f1 = *(const bfrag*)(xp + 32);
    } else {
      #pragma unroll
      for (int e = 0; e < 8; ++e) { f0[e] = 0; f1[e] = 0; }
    }
  };
  auto comp = [&](int nt, bfrag f0, bfrag f1) {
    const int ry = nt >> 2, col0 = (nt & 3) << 4;
    const int y  = r0 - 2 + ry;
    const bool valid = (y >= 0) && (y < HH);
    const int colb = col0 + 1 + lr;
    ffrag a0 = {0.f, 0.f, 0.f, 0.f}, a1 = {0.f, 0.f, 0.f, 0.f};
    a0 = __builtin_amdgcn_mfma_f32_16x16x32_bf16(w1h[0][0], f0, a0, 0, 0, 0);
    a0 = __builtin_amdgcn_mfma_f32_16x16x32_bf16(w1l[0][0], f0, a0, 0, 0, 0);
    a0 = __builtin_amdgcn_mfma_f32_16x16x32_bf16(w1h[0][1], f1, a0, 0, 0, 0);
    a0 = __builtin_amdgcn_mfma_f32_16x16x32_bf16(w1l[0][1], f1, a0, 0, 0, 0);
    a1 = __builtin_amdgcn_mfma_f32_16x16x32_bf16(w1h[1][0], f0, a1, 0, 0, 0);
    a1 = __builtin_amdgcn_mfma_f32_16x16x32_bf16(w1l[1][0], f0, a1, 0, 0, 0);
    a1 = __builtin_amdgcn_mfma_f32_16x16x32_bf16(w1h[1][1], f1, a1, 0, 0, 0);
    a1 = __builtin_amdgcn_mfma_f32_16x16x32_bf16(w1l[1][1], f1, a1, 0, 0, 0);
    #pragma unroll
    for (int m = 0; m < 2; ++m) {
      uint2 sv;
      if (valid) {
        float v0 = fmaxf((m ? a1[0] : a0[0]) + bias1[m][0], 0.f);
        float v1 = fmaxf((m ? a1[1] : a0[1]) + bias1[m][1], 0.f);
        float v2 = fmaxf((m ? a1[2] : a0[2]) + bias1[m][2], 0.f);
        float v3 = fmaxf((m ? a1[3] : a0[3]) + bias1[m][3], 0.f);
        sv = uint2{pack2(v0, v1), pack2(v2, v3)};
      } else {
        sv = uint2{0u, 0u};
      }
      int chunk = (m * 2 + (lg >> 1)) ^ ((colb >> 1) & 3);
      char* dst = smem + ((ry * 66 + colb) << 6) + (chunk << 4) + (lg & 1) * 8;
      *(uint2*)dst = sv;
    }
  };

  {
    bfrag c0, c1, n0, n1;
    ldfrag(wv * 12 + 0, c0, c1);
    #pragma unroll
    for (int i = 0; i < 12; ++i) {
      if (i < 11) ldfrag(wv * 12 + i + 1, n0, n1);
      comp(wv * 12 + i, c0, c1);
      c0 = n0; c1 = n1;
    }
  }
  __syncthreads();

  // W2 fragments from global (after barrier; keeps Phase-A VGPR low).
  bfrag w2h[9], w2l[9];
  #pragma unroll
  for (int t = 0; t < 9; ++t) {
    const float* wp = w12 + lr * 288 + t;
    #pragma unroll
    for (int e = 0; e < 8; ++e) {
      float v = wp[(lg * 8 + e) * 9];
      w2h[t][e] = (short)bf_trunc(v);
      w2l[t][e] = (short)f2bf(v - bf_truncf(v));
    }
  }
  float bias2[4];
  #pragma unroll
  for (int r = 0; r < 4; ++r) bias2[r] = b12[lg * 4 + r];

  // ---- Phase B: conv2 -> h2 fp16 in registers. 40 tiles (10 rows), 10/wave.
  // h2 row hy = r0-1+hryo uses h1 rows hryo..hryo+2 (h1 idx = y-(r0-2)).
  uint32_t ph0[10], ph1[10];
  #pragma unroll
  for (int i = 0; i < 10; ++i) {
    const int nt   = wv * 10 + i;
    const int hryo = nt >> 2;             // 0..9
    const int col0 = (nt & 3) << 4;
    ffrag acc = {0.f, 0.f, 0.f, 0.f};
    #pragma unroll
    for (int ky = 0; ky < 3; ++ky) {
      const int row = hryo + ky;
      #pragma unroll
      for (int kx = 0; kx < 3; ++kx) {
        const int colb  = col0 + lr + kx;
        const int chunk = lg ^ ((colb >> 1) & 3);
        const bfrag hv = *(const bfrag*)(smem + ((row * 66 + colb) << 6) + (chunk << 4));
        acc = __builtin_amdgcn_mfma_f32_16x16x32_bf16(w2h[ky * 3 + kx], hv, acc, 0, 0, 0);
        acc = __builtin_amdgcn_mfma_f32_16x16x32_bf16(w2l[ky * 3 + kx], hv, acc, 0, 0, 0);
      }
    }
    ph0[i] = packh2(fmaxf(acc[0] + bias2[0], 0.f), fmaxf(acc[1] + bias2[1], 0.f));
    ph1[i] = packh2(fmaxf(acc[2] + bias2[2], 0.f), fmaxf(acc[3] + bias2[3], 0.f));
  }
  __syncthreads();   // all h1 reads done; safe to overwrite smem

  // h2 regs -> LDS: [10 rows][64 px][16 ch fp16] = 20480 B at smem base.
  #pragma unroll
  for (int i = 0; i < 10; ++i) {
    const int nt   = wv * 10 + i;
    const int hryo = nt >> 2;
    const int col  = ((nt & 3) << 4) + lr;
    *(uint2*)(smem + ((hryo * 64 + col) << 5) + lg * 8) = uint2{ph0[i], ph1[i]};
  }
  __syncthreads();

  // ---- Phase C1: conv3 (1x1, 16->8) -> h3 fp32 LDS [10][64][9] @ +20480.
  float* h3b = (float*)(smem + 20480);
  for (int p = tid; p < 640; p += 256) {
    const int ry = p >> 6, wc = p & 63;
    const int y  = r0 - 1 + ry;
    float* hd = h3b + (ry * 64 + wc) * 9;
    if (y >= 0 && y < HH) {
      const uint4 ua = *(const uint4*)(smem + ((ry * 64 + wc) << 5));
      const uint4 ub = *(const uint4*)(smem + ((ry * 64 + wc) << 5) + 16);
      uint32_t uw[8] = {ua.x, ua.y, ua.z, ua.w, ub.x, ub.y, ub.z, ub.w};
      float xv[16];
      #pragma unroll
      for (int j = 0; j < 8; ++j) {
        xv[2*j]   = h2f(uw[j] & 0xffffu);
        xv[2*j+1] = h2f(uw[j] >> 16);
      }
      float acc[C3];
      #pragma unroll
      for (int o = 0; o < C3; ++o) acc[o] = b21[o];
      #pragma unroll
      for (int c = 0; c < 16; ++c) {
        float v = xv[c];
        #pragma unroll
        for (int o = 0; o < C3; ++o)
          acc[o] = fmaf(v, w21[o * 16 + c], acc[o]);   // uniform -> s_load
      }
      #pragma unroll
      for (int c = 0; c < C3; ++c) hd[c] = fmaxf(acc[c], 0.f);
    } else {
      #pragma unroll
      for (int c = 0; c < C3; ++c) hd[c] = 0.f;
    }
  }
  __syncthreads();

  // ---- Phase C2: conv4 (3x3, 8->4) -> h4 bf16 hi/lo global.
  for (int p = tid; p < 512; p += 256) {
    const int yl = p >> 6, wc = p & 63;
    float acc[C4] = {b22[0], b22[1], b22[2], b22[3]};
    #pragma unroll
    for (int ky = 0; ky < 3; ++ky) {
      #pragma unroll
      for (int kx = 0; kx < 3; ++kx) {
        const int wcc = wc + kx - 1;
        if (wcc < 0 || wcc >= WW) continue;
        const float* hb = h3b + ((yl + ky) * 64 + wcc) * 9;
        const int tap = ky * 3 + kx;
        #pragma unroll
        for (int c = 0; c < C3; ++c) {
          float v = hb[c];
          #pragma unroll
          for (int o = 0; o < C4; ++o)
            acc[o] = fmaf(v, w22[(o * 8 + c) * 9 + tap], acc[o]);  // s_load
        }
      }
    }
    const size_t base = (size_t)blockIdx.y * KFC + (r0 + yl) * WW + wc;
    #pragma unroll
    for (int o = 0; o < C4; ++o) {
      float v = fmaxf(acc[o], 0.f);
      h4h[base + (size_t)o * HW] = bf_trunc(v);
      h4l[base + (size_t)o * HW] = f2bf(v - bf_truncf(v));
    }
  }
}

// ---------------------------------------------------------------------------
// K2b: fcw fp32 -> bf16 hi/lo planes (once per launch, deterministic)
// ---------------------------------------------------------------------------
__global__ __launch_bounds__(256) void k_cvt_fcw(
    const float* __restrict__ w, ushort* __restrict__ hi, ushort* __restrict__ lo)
{
  const int i = (blockIdx.x * 256 + threadIdx.x) * 8;
  const float4 a = *(const float4*)(w + i);
  const float4 b = *(const float4*)(w + i + 4);
  uint4 hv, lv;
  hv.x = packhi2(a.x, a.y); hv.y = packhi2(a.z, a.w);
  hv.z = packhi2(b.x, b.y); hv.w = packhi2(b.z, b.w);
  lv.x = pack2(a.x - bf_truncf(a.x), a.y - bf_truncf(a.y));
  lv.y = pack2(a.z - bf_truncf(a.z), a.w - bf_truncf(a.w));
  lv.z = pack2(b.x - bf_truncf(b.x), b.y - bf_truncf(b.y));
  lv.w = pack2(b.z - bf_truncf(b.z), b.w - bf_truncf(b.w));
  *(uint4*)(hi + i) = hv;
  *(uint4*)(lo + i) = lv;
}

// ---------------------------------------------------------------------------
// K3: FC GEMM, MFMA bf16 3-product (hi/lo), K split KS-way, deterministic.
// ---------------------------------------------------------------------------
__global__ __launch_bounds__(256) void k_fc(
    const ushort* __restrict__ Ahp, const ushort* __restrict__ Alp,
    const ushort* __restrict__ Bhp, const ushort* __restrict__ Blp,
    float* __restrict__ zpart, int cb)
{
  const int tid = threadIdx.x;
  const int l   = tid & 63;
  const int wv  = tid >> 6;
  const int lr  = l & 15;
  const int lg  = l >> 4;
  const int m0  = blockIdx.x * 64 + (wv >> 1) * 32;
  const int n0  = blockIdx.y * 64 + (wv & 1) * 32;
  const int k0  = blockIdx.z * (KFC / KS);     // 512 per split

  int mrow[2], nrow[2];
  #pragma unroll
  for (int t = 0; t < 2; ++t) {
    int m = m0 + t * 16 + lr;
    mrow[t] = m < cb ? m : cb - 1;             // clamp; masked at write
    nrow[t] = n0 + t * 16 + lr;
  }
  ffrag acc[2][2] = {};

  #pragma unroll 1
  for (int kc = 0; kc < (KFC / KS) / 32; ++kc) {
    const int k = k0 + kc * 32 + lg * 8;
    bfrag ah[2], al[2], bh[2], bl[2];
    #pragma unroll
    for (int t = 0; t < 2; ++t) {
      ah[t] = *(const bfrag*)(Ahp + (size_t)mrow[t] * KFC + k);
      al[t] = *(const bfrag*)(Alp + (size_t)mrow[t] * KFC + k);
      bh[t] = *(const bfrag*)(Bhp + (size_t)nrow[t] * KFC + k);
      bl[t] = *(const bfrag*)(Blp + (size_t)nrow[t] * KFC + k);
    }
    #pragma unroll
    for (int mt = 0; mt < 2; ++mt) {
      #pragma unroll
      for (int nt = 0; nt < 2; ++nt) {
        acc[mt][nt] = __builtin_amdgcn_mfma_f32_16x16x32_bf16(ah[mt], bh[nt], acc[mt][nt], 0, 0, 0);
        acc[mt][nt] = __builtin_amdgcn_mfma_f32_16x16x32_bf16(ah[mt], bl[nt], acc[mt][nt], 0, 0, 0);
        acc[mt][nt] = __builtin_amdgcn_mfma_f32_16x16x32_bf16(al[mt], bh[nt], acc[mt][nt], 0, 0, 0);
      }
    }
  }

  #pragma unroll
  for (int mt = 0; mt < 2; ++mt) {
    #pragma unroll
    for (int r = 0; r < 4; ++r) {
      const int m = m0 + mt * 16 + lg * 4 + r;
      if (m < cb) {
        #pragma unroll
        for (int nt = 0; nt < 2; ++nt)
          zpart[((size_t)blockIdx.z * cb + m) * NOUT + n0 + nt * 16 + lr] = acc[mt][nt][r];
      }
    }
  }
}

// ---------------------------------------------------------------------------
// K5: fused coord + bilinear gather reading xt (NHWC bf16), XCD-grouped.
// ---------------------------------------------------------------------------
__global__ __launch_bounds__(256) void k_gather(
    const ushort* __restrict__ xt, const float* __restrict__ zpart,
    const float* __restrict__ fcb, float* __restrict__ out, int cb, int b0)
{
  const int bid = blockIdx.x;
  int bl, g;
  if ((cb & 7) == 0) {
    const int xcd = bid & 7;
    const int j   = bid >> 3;
    g  = j & 31;
    bl = (j >> 5) * 8 + xcd;
  } else {
    bl = bid >> 5;
    g  = bid & 31;
  }
  const int node = g * 4 + (threadIdx.x >> 6);
  const int l    = threadIdx.x & 63;
  const int bg   = b0 + bl;

  float val = 0.f;
  if (l < 2 * KS) {
    const int kb = l >> 1, comp = l & 1;
    val = zpart[((size_t)kb * cb + bl) * NOUT + node * 2 + comp];
  }
  #pragma unroll
  for (int off = 2; off < 2 * KS; off <<= 1) val += __shfl_xor(val, off);
  const float z0 = __shfl(val, 0) + fcb[node * 2 + 0];
  const float z1 = __shfl(val, 1) + fcb[node * 2 + 1];
  const float ch = 31.f / (1.f + __expf(-3.f * z0));
  const float cw = 63.f / (1.f + __expf(-3.f * z1));

  if (l < 2)
    out[GF_SIZE + (((size_t)bg * NODES + node) << 1) + l] = l ? cw : ch;

  const float chv = fminf(fmaxf(ch, 0.f), 31.f);
  const float cwv = fminf(fmaxf(cw, 0.f), 63.f);
  const float fh = floorf(chv), fw = floorf(cwv);
  const int h0 = (int)fh, h1i = (int)ceilf(chv);
  const int w0 = (int)fw, w1i = (int)ceilf(cwv);
  const float oh = chv - fh, ow = cwv - fw;
  const ushort* xbp = xt + (size_t)bg * HW * CIN + l;
  const float v_lt = bf2f(xbp[(size_t)(h0 * WW + w0) * CIN]);
  const float v_rt = bf2f(xbp[(size_t)(h1i * WW + w0) * CIN]);
  const float v_lb = bf2f(xbp[(size_t)(h0 * WW + w1i) * CIN]);
  const float v_rb = bf2f(xbp[(size_t)(h1i * WW + w1i) * CIN]);
  const float vt = v_lt + oh * (v_rt - v_lt);
  const float vb = v_lb + oh * (v_rb - v_lb);
  out[((size_t)bg * NODES + node) * CIN + l] = vt + ow * (vb - vt);
}

// ---------------------------------------------------------------------------
extern "C" void kernel_launch(void* const* d_in, const int* in_sizes, int n_in,
                              void* d_out, int out_size, void* d_ws, size_t ws_size,
                              hipStream_t stream)
{
  (void)in_sizes; (void)n_in; (void)out_size;
  const float* x   = (const float*)d_in[0];
  const float* w11 = (const float*)d_in[1];
  const float* b11 = (const float*)d_in[2];
  const float* w12 = (const float*)d_in[3];
  const float* b12 = (const float*)d_in[4];
  const float* w21 = (const float*)d_in[5];
  const float* b21 = (const float*)d_in[6];
  const float* w22 = (const float*)d_in[7];
  const float* b22 = (const float*)d_in[8];
  const float* fcw = (const float*)d_in[9];
  const float* fcb = (const float*)d_in[10];
  float* out = (float*)d_out;
  char* wsb  = (char*)d_ws;

  // fixed: xt (134 MB) + fcw hi/lo planes (8 MB). ws_size ~= 1 GiB.
  const size_t xtBytes = (size_t)BATCH * HW * CIN * 2;
  const size_t perB    = 16384 + 16384 + (size_t)KS * NOUT * 4;   // h4 hi/lo + zpart
  const size_t fixed   = xtBytes + 2 * 4194304;
  size_t avail = ws_size > fixed ? ws_size - fixed : perB;
  size_t cbmax = avail / perB;
  int CB = (int)(cbmax < (size_t)BATCH ? cbmax : (size_t)BATCH);
  if (CB < 1) CB = 1;

  char* p = wsb;
  ushort* xtv  = (ushort*)p;  p += xtBytes;
  ushort* h4h  = (ushort*)p;  p += (size_t)CB * 16384;
  ushort* h4l  = (ushort*)p;  p += (size_t)CB * 16384;
  float*  zpv  = (float*)p;   p += (size_t)CB * KS * NOUT * 4;
  ushort* fcwh = (ushort*)p;  p += 4194304;
  ushort* fcwl = (ushort*)p;

  k_cvt_fcw<<<dim3(NOUT * KFC / (256 * 8)), 256, 0, stream>>>(fcw, fcwh, fcwl);
  k_xpose<<<dim3(8, BATCH), 256, 0, stream>>>(x, xtv);

  for (int b0 = 0; b0 < BATCH; b0 += CB) {
    const int cb = (BATCH - b0 < CB) ? (BATCH - b0) : CB;
    k_conv1234<<<dim3(4, cb), 256, 0, stream>>>(xtv, w11, b11, w12, b12,
                                                w21, b21, w22, b22, h4h, h4l, b0);
    k_fc<<<dim3((cb + 63) / 64, 4, KS), 256, 0, stream>>>(h4h, h4l, fcwh, fcwl, zpv, cb);
    k_gather<<<dim3(cb * 32), 256, 0, stream>>>(xtv, zpv, fcb, out, cb, b0);
  }
}